// Round 10
// baseline (448.026 us; speedup 1.0000x reference)
//
#include <hip/hip_runtime.h>
#include <hip/hip_bf16.h>

typedef __hip_bfloat16 bf16;
typedef _Float16 f16;
typedef _Float16 f16x4 __attribute__((ext_vector_type(4)));
typedef float f32x4 __attribute__((ext_vector_type(4)));

#define HD 16
#define TK 128
#define KP 20

__device__ __forceinline__ float b2f(bf16 v){ return __bfloat162float(v); }
__device__ __forceinline__ float gelu_f(float x){ return 0.5f*x*(1.0f+erff(x*0.70710678118654752f)); }
__device__ __forceinline__ float rdv(const void* p, size_t i, bool bf){
  return bf ? b2f(((const bf16*)p)[i]) : ((const float*)p)[i];
}
__device__ __forceinline__ float4 ld4f(const void* p, size_t i, bool bf){
  if (bf){
    const bf16* q = (const bf16*)p + i;
    return make_float4(b2f(q[0]), b2f(q[1]), b2f(q[2]), b2f(q[3]));
  }
  return *(const float4*)((const float*)p + i);
}

// ---------------- inline dtype detector (R28: replaces detect_k dispatch) ----------------
// Wave-parallel, reads first 2KB f32 + 2KB bf16 of raw input (L2-hot). Same decision math
// as the old detect_k; ~80cyc/wave. All lanes return the same wave-uniform bool.
__device__ __forceinline__ bool detect_bf(const void* x){
  int l = threadIdx.x & 63;
  const float* xf = (const float*)x;
  const bf16*  xb = (const bf16*)x;
  float sF = 0.f, sB = 0.f;
  #pragma unroll
  for (int i = 0; i < 8; i++){ float v = fabsf(xf[l + i*64]);      if (!(v < 1e30f)) v = 1e30f; sF += v; }
  #pragma unroll
  for (int i = 0; i < 16; i++){ float v = fabsf(b2f(xb[l + i*64])); if (!(v < 1e30f)) v = 1e30f; sB += v; }
  #pragma unroll
  for (int o = 32; o; o >>= 1){ sF += __shfl_xor(sF, o); sB += __shfl_xor(sB, o); }
  float mF = sF/512.f, mB = sB/1024.f;
  float dF = fabsf(logf(fmaxf(mF, 1e-30f)));
  float dB = fabsf(logf(fmaxf(mB, 1e-30f)));
  return dB <= dF;
}

// ---------------- input -> fp32 convert ----------------
__global__ void cvt_k(const void* __restrict__ in, float* __restrict__ out, int n){
  bool bf = detect_bf(in);
  int i = blockIdx.x*blockDim.x + threadIdx.x;
  if (i < n) out[i] = rdv(in, i, bf);
}

// ---------------- wave-split LayerNorm (branch1 only; others use lnf-fused convs) ----------------
__global__ __launch_bounds__(256) void ln2dw_k(
    const float* __restrict__ x, const void* __restrict__ g,
    const void* __restrict__ b, float* __restrict__ y,
    int C, int HW, const void* __restrict__ xdet)
{
  __shared__ float redS[16][16];
  __shared__ float redQ[16][16];
  bool bf = detect_bf(xdet);
  int t = threadIdx.x, pix = t & 15, sub = t >> 4;
  int p  = blockIdx.x*16 + pix;
  int bb = blockIdx.y;
  const float* xb = x + (size_t)bb*C*HW + p;
  float xv[8];
  float s = 0.f, s2 = 0.f;
  #pragma unroll
  for (int i = 0; i < 8; i++){
    float v = xb[(size_t)(sub*8 + i)*HW];
    xv[i] = v; s += v; s2 += v*v;
  }
  redS[sub][pix] = s; redQ[sub][pix] = s2;
  __syncthreads();
  float st = 0.f, qt = 0.f;
  #pragma unroll
  for (int j = 0; j < 16; j++){ st += redS[j][pix]; qt += redQ[j][pix]; }
  float mu  = st / (float)C;
  float var = fmaxf(qt / (float)C - mu*mu, 0.f);
  float inv = rsqrtf(var + 1e-5f);
  float* yb = y + (size_t)bb*C*HW + p;
  #pragma unroll
  for (int i = 0; i < 8; i++){
    int c = sub*8 + i;
    yb[(size_t)c*HW] = (xv[i] - mu)*inv*rdv(g, c, bf) + rdv(b, c, bf);
  }
}

// ---------------- MFMA 1x1-conv GEMM (R27 4-wave; R28: +osplit dual-output merge) ----------------
// osplit>0: o-tiles at o0 >= osplit use weight w2 / output out2 (O2 rows) with local row
// o0-osplit. Region boundary must be a multiple of 64 so each block stays in one region
// (branches wave-uniform regardless). Used to merge kvx (O=256, head-norm on 0..127) and
// qx (O2=128) — same input P, same inline-LN. Other flags proven R25/R26.
__global__ __launch_bounds__(256) void convmfma_k(
    const float* __restrict__ in1, long in1_bs, int C1,
    const float* __restrict__ in2, long in2_bs, int C2,
    const void* __restrict__ w, const void* __restrict__ bias,
    const float* __restrict__ res, void* __restrict__ out, int to_out,
    int O, int NP, int act, int nlo, int nhi,
    int lnf, const void* __restrict__ lng, const void* __restrict__ lnb,
    int pool, int ups2,
    const void* __restrict__ w2, void* __restrict__ out2, int O2, int osplit,
    const void* __restrict__ xdet)
{
  bool bf = detect_bf(xdet);
  int lane = threadIdx.x & 63, wv = threadIdx.x >> 6;
  int lm = lane & 15, lg = (lane >> 4) & 3;
  int p0 = blockIdx.x*16, o0 = blockIdx.y*64 + wv*16, bb = blockIdx.z;
  int CW = C1 + C2;
  const void* wu = w; void* outu = out; int Ou = O; int od = 0;
  if (osplit > 0 && o0 >= osplit){ wu = w2; outu = out2; Ou = O2; od = osplit; }
  const float* x1 = in1 + (size_t)bb*in1_bs + p0 + lm;
  const float* x2b = in2 ? (in2 + (size_t)bb*in2_bs) : nullptr;
  // ups2 per-lane bilinear constants
  float fh = 0.f, fw = 0.f; int i00=0, i01=0, i10=0, i11=0;
  if (ups2){
    int p = p0 + lm; int hh = p/48, ww = p%48;
    float sh = hh*0.25f - 0.375f, sw = ww*0.25f - 0.375f;
    float fh0 = floorf(sh), fw0 = floorf(sw);
    fh = sh - fh0; fw = sw - fw0;
    int h0 = (int)fh0, w0 = (int)fw0;
    int h0c = min(11, max(0, h0)), h1c = min(11, max(0, h0+1));
    int w0c = min(11, max(0, w0)), w1c = min(11, max(0, w0+1));
    i00 = h0c*12 + w0c; i01 = h0c*12 + w1c; i10 = h1c*12 + w0c; i11 = h1c*12 + w1c;
  }
  // pool per-lane fine base
  const float* pN = nullptr;
  if (pool){
    int pc = p0 + lm; int hc = pc/12, wc = pc%12;
    pN = in1 + (size_t)bb*in1_bs + hc*192 + wc*4;
  }
  // inline LayerNorm stats (pixel = lm; lg groups cover c = lg, lg+4, ...)
  float mu = 0.f, linv = 0.f;
  if (lnf){
    float s = 0.f, s2 = 0.f;
    for (int c = lg; c < CW; c += 4){ float v = x1[(size_t)c*NP]; s += v; s2 += v*v; }
    s  += __shfl_xor(s, 16);  s  += __shfl_xor(s, 32);
    s2 += __shfl_xor(s2, 16); s2 += __shfl_xor(s2, 32);
    mu = s / (float)CW;
    float var = fmaxf(s2/(float)CW - mu*mu, 0.f);
    linv = rsqrtf(var + 1e-5f);
  }
  f32x4 d; d[0]=0.f; d[1]=0.f; d[2]=0.f; d[3]=0.f;
  #pragma unroll 4
  for (int kc = 0; kc < CW; kc += 16){
    f16x4 xb;
    #pragma unroll
    for (int i = 0; i < 4; i++){
      int c = kc + lg*4 + i;
      float v;
      if (pool){
        const float* s = pN + (size_t)c*2304;
        float a = 0.f;
        #pragma unroll
        for (int r = 0; r < 4; r++)
          #pragma unroll
          for (int cc = 0; cc < 4; cc++) a += s[r*48 + cc];
        v = a * 0.0625f;
      } else if (c < C1){
        v = x1[(size_t)c*NP];
        if (lnf) v = (v - mu)*linv*rdv(lng, c, bf) + rdv(lnb, c, bf);
      } else {
        int c2 = c - C1;
        if (ups2){
          const float* s = x2b + (size_t)c2*144;
          v = (1.f-fh)*((1.f-fw)*s[i00] + fw*s[i01]) + fh*((1.f-fw)*s[i10] + fw*s[i11]);
        } else {
          v = x2b[(size_t)c2*NP + p0 + lm];
        }
      }
      xb[i] = (f16)v;
    }
    float4 wv4 = ld4f(wu, (size_t)(o0 - od + lm)*CW + kc + lg*4, bf);
    f16x4 wa; wa[0]=(f16)wv4.x; wa[1]=(f16)wv4.y; wa[2]=(f16)wv4.z; wa[3]=(f16)wv4.w;
    d = __builtin_amdgcn_mfma_f32_16x16x16f16(wa, xb, d, 0, 0, 0);
  }
  if (o0 >= nlo && o0 < nhi){
    float ss = d[0]*d[0] + d[1]*d[1] + d[2]*d[2] + d[3]*d[3];
    ss += __shfl_xor(ss, 16); ss += __shfl_xor(ss, 32);
    float iv = 1.f / fmaxf(sqrtf(ss), 1e-12f);
    d[0]*=iv; d[1]*=iv; d[2]*=iv; d[3]*=iv;
  }
  #pragma unroll
  for (int r = 0; r < 4; r++){
    int o = o0 - od + lg*4 + r;          // local row in wu/outu
    float v = d[r] + (bias ? rdv(bias, o, bf) : 0.f);
    if (act == 1) v = gelu_f(v);
    size_t oi = ((size_t)bb*Ou + o)*NP + p0 + lm;
    if (res) v += res[oi];
    if (to_out && bf) ((bf16*)outu)[oi] = __float2bfloat16(v);
    else              ((float*)outu)[oi] = v;
  }
}

// ---------------- MFMA flash cosine attention (local attn, d=16; proven R22) ----------------
__global__ __launch_bounds__(512) void flat_mfma_k(
    const float* __restrict__ Q, long qbs, int qoff,
    const float* __restrict__ KV, long kbs, int koff, int voff,
    float* __restrict__ Out, long obs, int NQ, int NK, float scale)
{
  __shared__ float OS[8*4*16*17];
  __shared__ float LS[8*4*16];
  int t = threadIdx.x, lane = t & 63, wv = t >> 6;
  int h = blockIdx.y, bb = blockIdx.z;
  int qb = blockIdx.x*64;
  int lm = lane & 15, lg = lane >> 4;
  const float* qp  = Q  + (size_t)bb*qbs;
  const float* kvb = KV + (size_t)bb*kbs;
  f16x4 qf[4];
  #pragma unroll
  for (int qt = 0; qt < 4; qt++){
    float qv[4]; float ss = 0.f;
    #pragma unroll
    for (int i = 0; i < 4; i++){
      qv[i] = qp[(size_t)(qoff + h*16 + lg*4 + i)*NQ + qb + qt*16 + lm];
      ss += qv[i]*qv[i];
    }
    ss += __shfl_xor(ss, 16); ss += __shfl_xor(ss, 32);
    float inv = scale / fmaxf(sqrtf(ss), 1e-12f);
    #pragma unroll
    for (int i = 0; i < 4; i++) qf[qt][i] = (f16)(qv[i]*inv);
  }
  f32x4 of[4];
  float ls[4];
  #pragma unroll
  for (int qt = 0; qt < 4; qt++){
    of[qt][0]=0.f; of[qt][1]=0.f; of[qt][2]=0.f; of[qt][3]=0.f; ls[qt]=0.f;
  }
  int chunk = NK >> 3;
  int p0 = wv*chunk, p1 = p0 + chunk;
  const float* kc = kvb + (size_t)(koff + h*16)*NK;
  const float* vc = kvb + (size_t)(voff + h*16)*NK;
  for (int pos = p0; pos < p1; pos += 16){
    f16x4 kf;
    #pragma unroll
    for (int i = 0; i < 4; i++)
      kf[i] = (f16)kc[(size_t)(lg*4 + i)*NK + pos + lm];
    float4 vvv = *(const float4*)&vc[(size_t)lm*NK + pos + lg*4];
    f16x4 vf; vf[0]=(f16)vvv.x; vf[1]=(f16)vvv.y; vf[2]=(f16)vvv.z; vf[3]=(f16)vvv.w;
    #pragma unroll
    for (int qt = 0; qt < 4; qt++){
      f32x4 s; s[0]=0.f; s[1]=0.f; s[2]=0.f; s[3]=0.f;
      s = __builtin_amdgcn_mfma_f32_16x16x16f16(kf, qf[qt], s, 0, 0, 0);
      f16x4 pf;
      #pragma unroll
      for (int r = 0; r < 4; r++){
        float pp = __expf(s[r]);
        ls[qt] += pp;
        pf[r] = (f16)pp;
      }
      of[qt] = __builtin_amdgcn_mfma_f32_16x16x16f16(vf, pf, of[qt], 0, 0, 0);
    }
  }
  #pragma unroll
  for (int qt = 0; qt < 4; qt++){
    ls[qt] += __shfl_xor(ls[qt], 16);
    ls[qt] += __shfl_xor(ls[qt], 32);
    #pragma unroll
    for (int r = 0; r < 4; r++)
      OS[((wv*4 + qt)*16 + lm)*17 + lg*4 + r] = of[qt][r];
    if (lg == 0) LS[(wv*4 + qt)*16 + lm] = ls[qt];
  }
  __syncthreads();
  #pragma unroll
  for (int rep = 0; rep < 2; rep++){
    int o = t + rep*512;
    int d = o >> 6, qq = o & 63;
    int qt = qq >> 4, q = qq & 15;
    float acc = 0.f, lsum = 0.f;
    #pragma unroll
    for (int w = 0; w < 8; w++){
      acc  += OS[((w*4 + qt)*16 + q)*17 + d];
      lsum += LS[(w*4 + qt)*16 + q];
    }
    Out[(size_t)bb*obs + (size_t)(h*16 + d)*NQ + qb + qq] = acc / fmaxf(lsum, 1e-30f);
  }
}

// ---------------- attn4, no-max (global attn NK=144; proven) ----------------
__global__ __launch_bounds__(256) void attn4_k(
    const float* __restrict__ Q, long qbs, int qoff,
    const float* __restrict__ KV, long kbs, int koff, int voff,
    float* __restrict__ Out, long obs, int NQ, int NK, float scale)
{
  __shared__ __align__(16) float Ks[TK*KP];
  __shared__ __align__(16) float Vs[TK*KP];
  int tid = threadIdx.x;
  int sub = tid & 3;
  int h = blockIdx.y, bb = blockIdx.z;
  int qi = blockIdx.x*64 + (tid >> 2);
  bool qv = qi < NQ;
  float qn[4] = {0,0,0,0}, acc[4] = {0,0,0,0};
  float l = 0.f;
  if (qv){
    float s = 0.f;
    #pragma unroll
    for (int j = 0; j < 4; j++){
      qn[j] = Q[(size_t)bb*qbs + (size_t)(qoff + h*16 + sub*4 + j)*NQ + qi];
      s += qn[j]*qn[j];
    }
    s += __shfl_xor(s, 1); s += __shfl_xor(s, 2);
    float inv = scale / fmaxf(sqrtf(s), 1e-12f);
    #pragma unroll
    for (int j = 0; j < 4; j++) qn[j] *= inv;
  }
  for (int k0 = 0; k0 < NK; k0 += TK){
    int lim = min(TK, NK - k0);
    for (int i = tid; i < 16*TK; i += 256){
      int pos = i & (TK-1), d = i >> 7;
      if (pos < lim){
        Ks[pos*KP + d] = KV[(size_t)bb*kbs + (size_t)(koff + h*16 + d)*NK + k0 + pos];
        Vs[pos*KP + d] = KV[(size_t)bb*kbs + (size_t)(voff + h*16 + d)*NK + k0 + pos];
      }
    }
    __syncthreads();
    for (int pos = 0; pos < lim; pos++){
      float4 k4 = *(const float4*)&Ks[pos*KP + sub*4];
      float dd = qn[0]*k4.x + qn[1]*k4.y + qn[2]*k4.z + qn[3]*k4.w;
      dd += __shfl_xor(dd, 1); dd += __shfl_xor(dd, 2);
      float pp = __expf(dd);
      l += pp;
      float4 v4 = *(const float4*)&Vs[pos*KP + sub*4];
      acc[0] += pp*v4.x;
      acc[1] += pp*v4.y;
      acc[2] += pp*v4.z;
      acc[3] += pp*v4.w;
    }
    __syncthreads();
  }
  if (qv){
    float li = 1.f / fmaxf(l, 1e-30f);
    #pragma unroll
    for (int j = 0; j < 4; j++)
      Out[(size_t)bb*obs + (size_t)(h*16 + sub*4 + j)*NQ + qi] = acc[j]*li;
  }
}

// ---------------- xw attention with INLINE kvlat conv + K-norm (R28) ----------------
// Replaces {kvlat convmfma + normk + attn4(NK=16)}. 256 threads build the 16x16 K/V head
// tiles from latr via f32 MAC (more accurate than the f16 MFMA path it replaces), normalize
// K columns in-block, then run the proven attn4 NK=16 loop.
__global__ __launch_bounds__(256) void attn4lat_k(
    const float* __restrict__ Q, long qbs,
    const float* __restrict__ latr, const void* __restrict__ kvw,
    float* __restrict__ Out, long obs, int NQ, float scale,
    const void* __restrict__ xdet)
{
  __shared__ __align__(16) float Ks[16*KP];
  __shared__ __align__(16) float Vs[16*KP];
  bool bf = detect_bf(xdet);
  int tid = threadIdx.x;
  int h = blockIdx.y, bb = blockIdx.z;
  {
    int pos = tid & 15, d = tid >> 4;      // 256 threads cover the 16x16 tile
    const float* lr = latr + (size_t)bb*2048;
    float kk = 0.f, vv = 0.f;
    for (int c = 0; c < 128; c++){
      float xv = lr[(size_t)c*16 + pos];
      kk += rdv(kvw, (size_t)(h*16 + d)*128 + c, bf) * xv;
      vv += rdv(kvw, (size_t)(128 + h*16 + d)*128 + c, bf) * xv;
    }
    Ks[pos*KP + d] = kk;
    Vs[pos*KP + d] = vv;
  }
  __syncthreads();
  if (tid < 16){
    float ss = 0.f;
    #pragma unroll
    for (int d = 0; d < 16; d++){ float v = Ks[tid*KP + d]; ss += v*v; }
    float iv = 1.f / fmaxf(sqrtf(ss), 1e-12f);
    #pragma unroll
    for (int d = 0; d < 16; d++) Ks[tid*KP + d] *= iv;
  }
  __syncthreads();
  int sub = tid & 3;
  int qi = blockIdx.x*64 + (tid >> 2);
  float qn[4]; float acc[4] = {0,0,0,0}; float l = 0.f;
  {
    float s = 0.f;
    #pragma unroll
    for (int j = 0; j < 4; j++){
      qn[j] = Q[(size_t)bb*qbs + (size_t)(h*16 + sub*4 + j)*NQ + qi];
      s += qn[j]*qn[j];
    }
    s += __shfl_xor(s, 1); s += __shfl_xor(s, 2);
    float inv = scale / fmaxf(sqrtf(s), 1e-12f);
    #pragma unroll
    for (int j = 0; j < 4; j++) qn[j] *= inv;
  }
  for (int pos = 0; pos < 16; pos++){
    float4 k4 = *(const float4*)&Ks[pos*KP + sub*4];
    float dd = qn[0]*k4.x + qn[1]*k4.y + qn[2]*k4.z + qn[3]*k4.w;
    dd += __shfl_xor(dd, 1); dd += __shfl_xor(dd, 2);
    float pp = __expf(dd);
    l += pp;
    float4 v4 = *(const float4*)&Vs[pos*KP + sub*4];
    acc[0] += pp*v4.x;
    acc[1] += pp*v4.y;
    acc[2] += pp*v4.z;
    acc[3] += pp*v4.w;
  }
  float li = 1.f / fmaxf(l, 1e-30f);
  #pragma unroll
  for (int j = 0; j < 4; j++)
    Out[(size_t)bb*obs + (size_t)(h*16 + sub*4 + j)*NQ + qi] = acc[j]*li;
}

// ---------------- latent-read attention, split-K partials (R28: inline qlat conv) ----------------
__global__ void latpart_k(const void* __restrict__ lat, const void* __restrict__ qw,
                          const float* __restrict__ kvx, long kbs,
                          float* __restrict__ part, int NK, int S,
                          const void* __restrict__ xdet){
  __shared__ float qls[256];     // [d][q] for this head
  bool bf = detect_bf(xdet);
  int s = blockIdx.x, h = blockIdx.y, bb = blockIdx.z;
  int t = threadIdx.x;
  int q = t & 15, sub = (t >> 4) & 3;
  // build ql for head h: 256 values / 64 threads (identical math to the removed conv1x1)
  #pragma unroll
  for (int k2 = 0; k2 < 4; k2++){
    int v = t*4 + k2;
    int dd = v >> 4, qq = v & 15;
    float a = 0.f;
    for (int c = 0; c < 128; c++)
      a += rdv(qw, (size_t)(h*16 + dd)*128 + c, bf) * rdv(lat, (size_t)c*16 + qq, bf);
    qls[v] = a;
  }
  __syncthreads();
  float qn[16]; float ss = 0.f;
  #pragma unroll
  for (int d = 0; d < 16; d++){
    qn[d] = qls[d*16 + q];
    ss += qn[d]*qn[d];
  }
  float inv = 0.25f / fmaxf(sqrtf(ss), 1e-12f);
  #pragma unroll
  for (int d = 0; d < 16; d++) qn[d] *= inv;
  float l = 0.f, acc[16];
  #pragma unroll
  for (int d = 0; d < 16; d++) acc[d] = 0.f;
  int chunk = NK / S, c4 = chunk >> 2;
  int k0 = s*chunk + sub*c4, k1 = k0 + c4;
  const float* kb = kvx + (size_t)bb*kbs;
  for (int pos = k0; pos < k1; pos++){
    float dot = 0.f;
    #pragma unroll
    for (int d = 0; d < 16; d++) dot += qn[d]*kb[(size_t)(h*16+d)*NK + pos];
    float pp = __expf(dot);
    l += pp;
    #pragma unroll
    for (int d = 0; d < 16; d++)
      acc[d] += pp*kb[(size_t)(128 + h*16+d)*NK + pos];
  }
  l += __shfl_xor(l, 16); l += __shfl_xor(l, 32);
  #pragma unroll
  for (int d = 0; d < 16; d++){
    acc[d] += __shfl_xor(acc[d], 16);
    acc[d] += __shfl_xor(acc[d], 32);
  }
  if ((t >> 4) == 0){
    size_t idx = (size_t)((((bb*8 + h)*16 + q)*S) + s)*18;
    part[idx] = l;
    #pragma unroll
    for (int d = 0; d < 16; d++) part[idx+1+d] = acc[d];
  }
}

__global__ void latcomb_k(const float* __restrict__ part, float* __restrict__ latr, int S){
  int i = blockIdx.x*blockDim.x + threadIdx.x;   // 4096 total
  int d = i & 15, q = (i >> 4) & 15, h = (i >> 8) & 7, bb = i >> 11;
  size_t base = (size_t)(((bb*8 + h)*16 + q)*S)*18;
  float L = 0.f, a = 0.f;
  for (int s = 0; s < S; s++){
    const float* ps = part + base + (size_t)s*18;
    L += ps[0];
    a += ps[1+d];
  }
  latr[(size_t)bb*2048 + (size_t)(h*16+d)*16 + q] = a / fmaxf(L, 1e-30f);
}

extern "C" void kernel_launch(void* const* d_in, const int* in_sizes, int n_in,
                              void* d_out, int out_size, void* d_ws, size_t ws_size,
                              hipStream_t stream){
  const int B = 2, C = 128, HW = 2304;
  const void* x_in        = d_in[0];
  const void* g1          = d_in[1];
  const void* b1          = d_in[2];
  const void* loc_qkv_w   = d_in[3];
  const void* loc_proj_w  = d_in[4];
  const void* loc_proj_b  = d_in[5];
  const void* glob_qkv_w  = d_in[6];
  const void* glob_proj_w = d_in[7];
  const void* glob_proj_b = d_in[8];
  const void* fuse_w1     = d_in[9];
  const void* fuse_b1     = d_in[10];
  const void* fuse_w2     = d_in[11];
  const void* fuse_b2     = d_in[12];
  const void* glat        = d_in[13];
  const void* blat        = d_in[14];
  const void* latents     = d_in[15];
  const void* qlat_w      = d_in[16];
  const void* kvx_w       = d_in[17];
  const void* qx_w        = d_in[18];
  const void* kvlat_w     = d_in[19];
  const void* lat_proj_w  = d_in[20];
  const void* lat_proj_b  = d_in[21];
  const void* g2          = d_in[22];
  const void* b2          = d_in[23];
  const void* ffn_w1      = d_in[24];
  const void* ffn_b1      = d_in[25];
  const void* ffn_w2      = d_in[26];
  const void* ffn_b2      = d_in[27];

  // ---- workspace layout VERBATIM (R8..R18) ----
  float* ws = (float*)d_ws;
  float* P  = ws + 0;
  float* N  = ws + 589824;
  float* A  = ws + 1179648;
  float* Q  = ws + 1769472;

  float* qkv   = Q;                 // 1,769,472
  float* L     = Q + 1769472;       // 589,824
  float* qkvc  = Q + 36864;
  float* gatt  = Q + 147456;
  float* gproj = Q + 184320;
  float* kvx   = Q;                 // 1,179,648
  float* latr  = Q + 1185792;
  float* part  = Q + 1198080;       // 221,184 (S=48)
  float* ffh   = Q;                 // 2,359,296

  dim3 blk(256);
  dim3 blk512(512);

  cvt_k<<<2304, blk, 0, stream>>>(x_in, P, 589824);

  // ---- BioAttentionFusion branch ----
  ln2dw_k<<<dim3(144,B), blk, 0, stream>>>(P, g1, b1, N, C, HW, x_in);
  convmfma_k<<<dim3(144,6,B), blk, 0, stream>>>(N,(long)C*HW,C, nullptr,0,0, loc_qkv_w,nullptr,nullptr, qkv,0,384,HW,0, 128,256, 0,nullptr,nullptr, 0,0, nullptr,nullptr,0,0, x_in);
  flat_mfma_k<<<dim3(36,8,B), blk512, 0, stream>>>(qkv,(long)384*HW,0, qkv,(long)384*HW,128,256, A,(long)C*HW, HW,HW,0.25f);
  convmfma_k<<<dim3(144,2,B), blk, 0, stream>>>(A,(long)C*HW,C, nullptr,0,0, loc_proj_w,loc_proj_b,nullptr, L,0,C,HW,0, 0,0, 0,nullptr,nullptr, 0,0, nullptr,nullptr,0,0, x_in);
  // pooled global qkv: pool4 + conv + normk fused (pool reads LN'd N; K heads unit-normed)
  convmfma_k<<<dim3(9,6,B), blk, 0, stream>>>(N,(long)C*HW,C, nullptr,0,0, glob_qkv_w,nullptr,nullptr, qkvc,0,384,144,0, 128,256, 0,nullptr,nullptr, 1,0, nullptr,nullptr,0,0, x_in);
  attn4_k<<<dim3(3,8,B), blk, 0, stream>>>(qkvc,(long)384*144,0, qkvc,(long)384*144,128,256, gatt,(long)C*144, 144,144,0.25f);
  convmfma_k<<<dim3(9,2,B), blk, 0, stream>>>(gatt,(long)C*144,C, nullptr,0,0, glob_proj_w,glob_proj_b,nullptr, gproj,0,C,144,0, 0,0, 0,nullptr,nullptr, 0,0, nullptr,nullptr,0,0, x_in);
  // fuse1: in2 = gproj with inline bilinear upsample
  convmfma_k<<<dim3(144,2,B), blk, 0, stream>>>(L,(long)C*HW,C, gproj,(long)C*144,C, fuse_w1,fuse_b1,nullptr, N,0,C,HW,1, 0,0, 0,nullptr,nullptr, 0,1, nullptr,nullptr,0,0, x_in);
  convmfma_k<<<dim3(144,2,B), blk, 0, stream>>>(N,(long)C*HW,C, nullptr,0,0, fuse_w2,fuse_b2,P, P,0,C,HW,0, 0,0, 0,nullptr,nullptr, 0,0, nullptr,nullptr,0,0, x_in);

  // ---- LatentMixer branch (LN fused; kvx+qx merged via osplit) ----
  convmfma_k<<<dim3(144,6,B), blk, 0, stream>>>(P,(long)C*HW,C, nullptr,0,0, kvx_w,nullptr,nullptr, kvx,0,256,HW,0, 0,128, 1,glat,blat, 0,0, qx_w,A,128,256, x_in);
  latpart_k<<<dim3(48,8,B), 64, 0, stream>>>(latents, qlat_w, kvx, (long)256*HW, part, HW, 48, x_in);
  latcomb_k<<<16, blk, 0, stream>>>(part, latr, 48);
  attn4lat_k<<<dim3(36,8,B), blk, 0, stream>>>(A,(long)C*HW, latr, kvlat_w, N,(long)C*HW, HW, 0.25f, x_in);   // N = xw
  convmfma_k<<<dim3(144,2,B), blk, 0, stream>>>(N,(long)C*HW,C, nullptr,0,0, lat_proj_w,lat_proj_b,P, P,0,C,HW,0, 0,0, 0,nullptr,nullptr, 0,0, nullptr,nullptr,0,0, x_in); // P = x2

  // ---- FFN branch (LN fused into ffn1) ----
  convmfma_k<<<dim3(144,8,B), blk, 0, stream>>>(P,(long)C*HW,C, nullptr,0,0, ffn_w1,ffn_b1,nullptr, ffh,0,512,HW,1, 0,0, 1,g2,b2, 0,0, nullptr,nullptr,0,0, x_in);
  convmfma_k<<<dim3(144,2,B), blk, 0, stream>>>(ffh,(long)512*HW,512, nullptr,0,0, ffn_w2,ffn_b2,P, d_out,1,C,HW,0, 0,0, 0,nullptr,nullptr, 0,0, nullptr,nullptr,0,0, x_in);
}

// Round 11
// 443.843 us; speedup vs baseline: 1.0094x; 1.0094x over previous
//
#include <hip/hip_runtime.h>
#include <hip/hip_bf16.h>

typedef __hip_bfloat16 bf16;
typedef _Float16 f16;
typedef _Float16 f16x4 __attribute__((ext_vector_type(4)));
typedef float f32x4 __attribute__((ext_vector_type(4)));

#define HD 16
#define TK 128
#define KP 20

__device__ __forceinline__ float b2f(bf16 v){ return __bfloat162float(v); }
__device__ __forceinline__ float gelu_f(float x){ return 0.5f*x*(1.0f+erff(x*0.70710678118654752f)); }
__device__ __forceinline__ float rdv(const void* p, size_t i, bool bf){
  return bf ? b2f(((const bf16*)p)[i]) : ((const float*)p)[i];
}
__device__ __forceinline__ float4 ld4f(const void* p, size_t i, bool bf){
  if (bf){
    const bf16* q = (const bf16*)p + i;
    return make_float4(b2f(q[0]), b2f(q[1]), b2f(q[2]), b2f(q[3]));
  }
  return *(const float4*)((const float*)p + i);
}

// ---------------- inline dtype detector (proven R28) ----------------
__device__ __forceinline__ bool detect_bf(const void* x){
  int l = threadIdx.x & 63;
  const float* xf = (const float*)x;
  const bf16*  xb = (const bf16*)x;
  float sF = 0.f, sB = 0.f;
  #pragma unroll
  for (int i = 0; i < 8; i++){ float v = fabsf(xf[l + i*64]);      if (!(v < 1e30f)) v = 1e30f; sF += v; }
  #pragma unroll
  for (int i = 0; i < 16; i++){ float v = fabsf(b2f(xb[l + i*64])); if (!(v < 1e30f)) v = 1e30f; sB += v; }
  #pragma unroll
  for (int o = 32; o; o >>= 1){ sF += __shfl_xor(sF, o); sB += __shfl_xor(sB, o); }
  float mF = sF/512.f, mB = sB/1024.f;
  float dF = fabsf(logf(fmaxf(mF, 1e-30f)));
  float dB = fabsf(logf(fmaxf(mB, 1e-30f)));
  return dB <= dF;
}

// ---------------- input -> fp32 convert ----------------
__global__ void cvt_k(const void* __restrict__ in, float* __restrict__ out, int n){
  bool bf = detect_bf(in);
  int i = blockIdx.x*blockDim.x + threadIdx.x;
  if (i < n) out[i] = rdv(in, i, bf);
}

// ---------------- wave-split LayerNorm (branch1 only) ----------------
__global__ __launch_bounds__(256) void ln2dw_k(
    const float* __restrict__ x, const void* __restrict__ g,
    const void* __restrict__ b, float* __restrict__ y,
    int C, int HW, const void* __restrict__ xdet)
{
  __shared__ float redS[16][16];
  __shared__ float redQ[16][16];
  bool bf = detect_bf(xdet);
  int t = threadIdx.x, pix = t & 15, sub = t >> 4;
  int p  = blockIdx.x*16 + pix;
  int bb = blockIdx.y;
  const float* xb = x + (size_t)bb*C*HW + p;
  float xv[8];
  float s = 0.f, s2 = 0.f;
  #pragma unroll
  for (int i = 0; i < 8; i++){
    float v = xb[(size_t)(sub*8 + i)*HW];
    xv[i] = v; s += v; s2 += v*v;
  }
  redS[sub][pix] = s; redQ[sub][pix] = s2;
  __syncthreads();
  float st = 0.f, qt = 0.f;
  #pragma unroll
  for (int j = 0; j < 16; j++){ st += redS[j][pix]; qt += redQ[j][pix]; }
  float mu  = st / (float)C;
  float var = fmaxf(qt / (float)C - mu*mu, 0.f);
  float inv = rsqrtf(var + 1e-5f);
  float* yb = y + (size_t)bb*C*HW + p;
  #pragma unroll
  for (int i = 0; i < 8; i++){
    int c = sub*8 + i;
    yb[(size_t)c*HW] = (xv[i] - mu)*inv*rdv(g, c, bf) + rdv(b, c, bf);
  }
}

// ---------------- qlat conv (R29: restored as dedicated kernel; R10's inline version was
// recomputed 48x by latpart's split-K blocks — removed a 5us dispatch, added 30us) ----------------
__global__ __launch_bounds__(256) void qlat_k(
    const void* __restrict__ lat, const void* __restrict__ qw,
    float* __restrict__ qlat, const void* __restrict__ xdet)
{
  bool bf = detect_bf(xdet);
  int hb = blockIdx.x;           // 16 = (bb*8 + h)
  int bb = hb >> 3, h = hb & 7;
  int t = threadIdx.x;           // 256 = 16d x 16q
  int d = t >> 4, q = t & 15;
  float a = 0.f;
  for (int c = 0; c < 128; c++)
    a += rdv(qw, (size_t)(h*16 + d)*128 + c, bf) * rdv(lat, (size_t)c*16 + q, bf);
  qlat[(size_t)bb*2048 + (size_t)(h*16 + d)*16 + q] = a;
}

// ---------------- MFMA 1x1-conv GEMM (R27 4-wave; R28 osplit; proven flags) ----------------
__global__ __launch_bounds__(256) void convmfma_k(
    const float* __restrict__ in1, long in1_bs, int C1,
    const float* __restrict__ in2, long in2_bs, int C2,
    const void* __restrict__ w, const void* __restrict__ bias,
    const float* __restrict__ res, void* __restrict__ out, int to_out,
    int O, int NP, int act, int nlo, int nhi,
    int lnf, const void* __restrict__ lng, const void* __restrict__ lnb,
    int pool, int ups2,
    const void* __restrict__ w2, void* __restrict__ out2, int O2, int osplit,
    const void* __restrict__ xdet)
{
  bool bf = detect_bf(xdet);
  int lane = threadIdx.x & 63, wv = threadIdx.x >> 6;
  int lm = lane & 15, lg = (lane >> 4) & 3;
  int p0 = blockIdx.x*16, o0 = blockIdx.y*64 + wv*16, bb = blockIdx.z;
  int CW = C1 + C2;
  const void* wu = w; void* outu = out; int Ou = O; int od = 0;
  if (osplit > 0 && o0 >= osplit){ wu = w2; outu = out2; Ou = O2; od = osplit; }
  const float* x1 = in1 + (size_t)bb*in1_bs + p0 + lm;
  const float* x2b = in2 ? (in2 + (size_t)bb*in2_bs) : nullptr;
  float fh = 0.f, fw = 0.f; int i00=0, i01=0, i10=0, i11=0;
  if (ups2){
    int p = p0 + lm; int hh = p/48, ww = p%48;
    float sh = hh*0.25f - 0.375f, sw = ww*0.25f - 0.375f;
    float fh0 = floorf(sh), fw0 = floorf(sw);
    fh = sh - fh0; fw = sw - fw0;
    int h0 = (int)fh0, w0 = (int)fw0;
    int h0c = min(11, max(0, h0)), h1c = min(11, max(0, h0+1));
    int w0c = min(11, max(0, w0)), w1c = min(11, max(0, w0+1));
    i00 = h0c*12 + w0c; i01 = h0c*12 + w1c; i10 = h1c*12 + w0c; i11 = h1c*12 + w1c;
  }
  const float* pN = nullptr;
  if (pool){
    int pc = p0 + lm; int hc = pc/12, wc = pc%12;
    pN = in1 + (size_t)bb*in1_bs + hc*192 + wc*4;
  }
  float mu = 0.f, linv = 0.f;
  if (lnf){
    float s = 0.f, s2 = 0.f;
    for (int c = lg; c < CW; c += 4){ float v = x1[(size_t)c*NP]; s += v; s2 += v*v; }
    s  += __shfl_xor(s, 16);  s  += __shfl_xor(s, 32);
    s2 += __shfl_xor(s2, 16); s2 += __shfl_xor(s2, 32);
    mu = s / (float)CW;
    float var = fmaxf(s2/(float)CW - mu*mu, 0.f);
    linv = rsqrtf(var + 1e-5f);
  }
  f32x4 d; d[0]=0.f; d[1]=0.f; d[2]=0.f; d[3]=0.f;
  #pragma unroll 4
  for (int kc = 0; kc < CW; kc += 16){
    f16x4 xb;
    #pragma unroll
    for (int i = 0; i < 4; i++){
      int c = kc + lg*4 + i;
      float v;
      if (pool){
        const float* s = pN + (size_t)c*2304;
        float a = 0.f;
        #pragma unroll
        for (int r = 0; r < 4; r++)
          #pragma unroll
          for (int cc = 0; cc < 4; cc++) a += s[r*48 + cc];
        v = a * 0.0625f;
      } else if (c < C1){
        v = x1[(size_t)c*NP];
        if (lnf) v = (v - mu)*linv*rdv(lng, c, bf) + rdv(lnb, c, bf);
      } else {
        int c2 = c - C1;
        if (ups2){
          const float* s = x2b + (size_t)c2*144;
          v = (1.f-fh)*((1.f-fw)*s[i00] + fw*s[i01]) + fh*((1.f-fw)*s[i10] + fw*s[i11]);
        } else {
          v = x2b[(size_t)c2*NP + p0 + lm];
        }
      }
      xb[i] = (f16)v;
    }
    float4 wv4 = ld4f(wu, (size_t)(o0 - od + lm)*CW + kc + lg*4, bf);
    f16x4 wa; wa[0]=(f16)wv4.x; wa[1]=(f16)wv4.y; wa[2]=(f16)wv4.z; wa[3]=(f16)wv4.w;
    d = __builtin_amdgcn_mfma_f32_16x16x16f16(wa, xb, d, 0, 0, 0);
  }
  if (o0 >= nlo && o0 < nhi){
    float ss = d[0]*d[0] + d[1]*d[1] + d[2]*d[2] + d[3]*d[3];
    ss += __shfl_xor(ss, 16); ss += __shfl_xor(ss, 32);
    float iv = 1.f / fmaxf(sqrtf(ss), 1e-12f);
    d[0]*=iv; d[1]*=iv; d[2]*=iv; d[3]*=iv;
  }
  #pragma unroll
  for (int r = 0; r < 4; r++){
    int o = o0 - od + lg*4 + r;
    float v = d[r] + (bias ? rdv(bias, o, bf) : 0.f);
    if (act == 1) v = gelu_f(v);
    size_t oi = ((size_t)bb*Ou + o)*NP + p0 + lm;
    if (res) v += res[oi];
    if (to_out && bf) ((bf16*)outu)[oi] = __float2bfloat16(v);
    else              ((float*)outu)[oi] = v;
  }
}

// ---------------- MFMA flash cosine attention (local attn, d=16; proven R22) ----------------
__global__ __launch_bounds__(512) void flat_mfma_k(
    const float* __restrict__ Q, long qbs, int qoff,
    const float* __restrict__ KV, long kbs, int koff, int voff,
    float* __restrict__ Out, long obs, int NQ, int NK, float scale)
{
  __shared__ float OS[8*4*16*17];
  __shared__ float LS[8*4*16];
  int t = threadIdx.x, lane = t & 63, wv = t >> 6;
  int h = blockIdx.y, bb = blockIdx.z;
  int qb = blockIdx.x*64;
  int lm = lane & 15, lg = lane >> 4;
  const float* qp  = Q  + (size_t)bb*qbs;
  const float* kvb = KV + (size_t)bb*kbs;
  f16x4 qf[4];
  #pragma unroll
  for (int qt = 0; qt < 4; qt++){
    float qv[4]; float ss = 0.f;
    #pragma unroll
    for (int i = 0; i < 4; i++){
      qv[i] = qp[(size_t)(qoff + h*16 + lg*4 + i)*NQ + qb + qt*16 + lm];
      ss += qv[i]*qv[i];
    }
    ss += __shfl_xor(ss, 16); ss += __shfl_xor(ss, 32);
    float inv = scale / fmaxf(sqrtf(ss), 1e-12f);
    #pragma unroll
    for (int i = 0; i < 4; i++) qf[qt][i] = (f16)(qv[i]*inv);
  }
  f32x4 of[4];
  float ls[4];
  #pragma unroll
  for (int qt = 0; qt < 4; qt++){
    of[qt][0]=0.f; of[qt][1]=0.f; of[qt][2]=0.f; of[qt][3]=0.f; ls[qt]=0.f;
  }
  int chunk = NK >> 3;
  int p0 = wv*chunk, p1 = p0 + chunk;
  const float* kc = kvb + (size_t)(koff + h*16)*NK;
  const float* vc = kvb + (size_t)(voff + h*16)*NK;
  for (int pos = p0; pos < p1; pos += 16){
    f16x4 kf;
    #pragma unroll
    for (int i = 0; i < 4; i++)
      kf[i] = (f16)kc[(size_t)(lg*4 + i)*NK + pos + lm];
    float4 vvv = *(const float4*)&vc[(size_t)lm*NK + pos + lg*4];
    f16x4 vf; vf[0]=(f16)vvv.x; vf[1]=(f16)vvv.y; vf[2]=(f16)vvv.z; vf[3]=(f16)vvv.w;
    #pragma unroll
    for (int qt = 0; qt < 4; qt++){
      f32x4 s; s[0]=0.f; s[1]=0.f; s[2]=0.f; s[3]=0.f;
      s = __builtin_amdgcn_mfma_f32_16x16x16f16(kf, qf[qt], s, 0, 0, 0);
      f16x4 pf;
      #pragma unroll
      for (int r = 0; r < 4; r++){
        float pp = __expf(s[r]);
        ls[qt] += pp;
        pf[r] = (f16)pp;
      }
      of[qt] = __builtin_amdgcn_mfma_f32_16x16x16f16(vf, pf, of[qt], 0, 0, 0);
    }
  }
  #pragma unroll
  for (int qt = 0; qt < 4; qt++){
    ls[qt] += __shfl_xor(ls[qt], 16);
    ls[qt] += __shfl_xor(ls[qt], 32);
    #pragma unroll
    for (int r = 0; r < 4; r++)
      OS[((wv*4 + qt)*16 + lm)*17 + lg*4 + r] = of[qt][r];
    if (lg == 0) LS[(wv*4 + qt)*16 + lm] = ls[qt];
  }
  __syncthreads();
  #pragma unroll
  for (int rep = 0; rep < 2; rep++){
    int o = t + rep*512;
    int d = o >> 6, qq = o & 63;
    int qt = qq >> 4, q = qq & 15;
    float acc = 0.f, lsum = 0.f;
    #pragma unroll
    for (int w = 0; w < 8; w++){
      acc  += OS[((w*4 + qt)*16 + q)*17 + d];
      lsum += LS[(w*4 + qt)*16 + q];
    }
    Out[(size_t)bb*obs + (size_t)(h*16 + d)*NQ + qb + qq] = acc / fmaxf(lsum, 1e-30f);
  }
}

// ---------------- attn4, no-max (global attn NK=144; proven) ----------------
__global__ __launch_bounds__(256) void attn4_k(
    const float* __restrict__ Q, long qbs, int qoff,
    const float* __restrict__ KV, long kbs, int koff, int voff,
    float* __restrict__ Out, long obs, int NQ, int NK, float scale)
{
  __shared__ __align__(16) float Ks[TK*KP];
  __shared__ __align__(16) float Vs[TK*KP];
  int tid = threadIdx.x;
  int sub = tid & 3;
  int h = blockIdx.y, bb = blockIdx.z;
  int qi = blockIdx.x*64 + (tid >> 2);
  bool qv = qi < NQ;
  float qn[4] = {0,0,0,0}, acc[4] = {0,0,0,0};
  float l = 0.f;
  if (qv){
    float s = 0.f;
    #pragma unroll
    for (int j = 0; j < 4; j++){
      qn[j] = Q[(size_t)bb*qbs + (size_t)(qoff + h*16 + sub*4 + j)*NQ + qi];
      s += qn[j]*qn[j];
    }
    s += __shfl_xor(s, 1); s += __shfl_xor(s, 2);
    float inv = scale / fmaxf(sqrtf(s), 1e-12f);
    #pragma unroll
    for (int j = 0; j < 4; j++) qn[j] *= inv;
  }
  for (int k0 = 0; k0 < NK; k0 += TK){
    int lim = min(TK, NK - k0);
    for (int i = tid; i < 16*TK; i += 256){
      int pos = i & (TK-1), d = i >> 7;
      if (pos < lim){
        Ks[pos*KP + d] = KV[(size_t)bb*kbs + (size_t)(koff + h*16 + d)*NK + k0 + pos];
        Vs[pos*KP + d] = KV[(size_t)bb*kbs + (size_t)(voff + h*16 + d)*NK + k0 + pos];
      }
    }
    __syncthreads();
    for (int pos = 0; pos < lim; pos++){
      float4 k4 = *(const float4*)&Ks[pos*KP + sub*4];
      float dd = qn[0]*k4.x + qn[1]*k4.y + qn[2]*k4.z + qn[3]*k4.w;
      dd += __shfl_xor(dd, 1); dd += __shfl_xor(dd, 2);
      float pp = __expf(dd);
      l += pp;
      float4 v4 = *(const float4*)&Vs[pos*KP + sub*4];
      acc[0] += pp*v4.x;
      acc[1] += pp*v4.y;
      acc[2] += pp*v4.z;
      acc[3] += pp*v4.w;
    }
    __syncthreads();
  }
  if (qv){
    float li = 1.f / fmaxf(l, 1e-30f);
    #pragma unroll
    for (int j = 0; j < 4; j++)
      Out[(size_t)bb*obs + (size_t)(h*16 + sub*4 + j)*NQ + qi] = acc[j]*li;
  }
}

// ---------------- xw attention with INLINE kvlat conv + K-norm (proven R28) ----------------
__global__ __launch_bounds__(256) void attn4lat_k(
    const float* __restrict__ Q, long qbs,
    const float* __restrict__ latr, const void* __restrict__ kvw,
    float* __restrict__ Out, long obs, int NQ, float scale,
    const void* __restrict__ xdet)
{
  __shared__ __align__(16) float Ks[16*KP];
  __shared__ __align__(16) float Vs[16*KP];
  bool bf = detect_bf(xdet);
  int tid = threadIdx.x;
  int h = blockIdx.y, bb = blockIdx.z;
  {
    int pos = tid & 15, d = tid >> 4;
    const float* lr = latr + (size_t)bb*2048;
    float kk = 0.f, vv = 0.f;
    for (int c = 0; c < 128; c++){
      float xv = lr[(size_t)c*16 + pos];
      kk += rdv(kvw, (size_t)(h*16 + d)*128 + c, bf) * xv;
      vv += rdv(kvw, (size_t)(128 + h*16 + d)*128 + c, bf) * xv;
    }
    Ks[pos*KP + d] = kk;
    Vs[pos*KP + d] = vv;
  }
  __syncthreads();
  if (tid < 16){
    float ss = 0.f;
    #pragma unroll
    for (int d = 0; d < 16; d++){ float v = Ks[tid*KP + d]; ss += v*v; }
    float iv = 1.f / fmaxf(sqrtf(ss), 1e-12f);
    #pragma unroll
    for (int d = 0; d < 16; d++) Ks[tid*KP + d] *= iv;
  }
  __syncthreads();
  int sub = tid & 3;
  int qi = blockIdx.x*64 + (tid >> 2);
  float qn[4]; float acc[4] = {0,0,0,0}; float l = 0.f;
  {
    float s = 0.f;
    #pragma unroll
    for (int j = 0; j < 4; j++){
      qn[j] = Q[(size_t)bb*qbs + (size_t)(h*16 + sub*4 + j)*NQ + qi];
      s += qn[j]*qn[j];
    }
    s += __shfl_xor(s, 1); s += __shfl_xor(s, 2);
    float inv = scale / fmaxf(sqrtf(s), 1e-12f);
    #pragma unroll
    for (int j = 0; j < 4; j++) qn[j] *= inv;
  }
  for (int pos = 0; pos < 16; pos++){
    float4 k4 = *(const float4*)&Ks[pos*KP + sub*4];
    float dd = qn[0]*k4.x + qn[1]*k4.y + qn[2]*k4.z + qn[3]*k4.w;
    dd += __shfl_xor(dd, 1); dd += __shfl_xor(dd, 2);
    float pp = __expf(dd);
    l += pp;
    float4 v4 = *(const float4*)&Vs[pos*KP + sub*4];
    acc[0] += pp*v4.x;
    acc[1] += pp*v4.y;
    acc[2] += pp*v4.z;
    acc[3] += pp*v4.w;
  }
  float li = 1.f / fmaxf(l, 1e-30f);
  #pragma unroll
  for (int j = 0; j < 4; j++)
    Out[(size_t)bb*obs + (size_t)(h*16 + sub*4 + j)*NQ + qi] = acc[j]*li;
}

// ---------------- latent-read attention, split-K partials (R29: qlat from global, S=144) ----------------
__global__ void latpart_k(const float* __restrict__ ql, const float* __restrict__ kvx,
                          long kbs, float* __restrict__ part, int NK, int S){
  int s = blockIdx.x, h = blockIdx.y, bb = blockIdx.z;
  int t = threadIdx.x;
  int q = t & 15, sub = (t >> 4) & 3;
  float qn[16]; float ss = 0.f;
  #pragma unroll
  for (int d = 0; d < 16; d++){
    qn[d] = ql[(size_t)bb*2048 + (size_t)(h*16+d)*16 + q];
    ss += qn[d]*qn[d];
  }
  float inv = 0.25f / fmaxf(sqrtf(ss), 1e-12f);
  #pragma unroll
  for (int d = 0; d < 16; d++) qn[d] *= inv;
  float l = 0.f, acc[16];
  #pragma unroll
  for (int d = 0; d < 16; d++) acc[d] = 0.f;
  int chunk = NK / S, c4 = chunk >> 2;
  int k0 = s*chunk + sub*c4, k1 = k0 + c4;
  const float* kb = kvx + (size_t)bb*kbs;
  for (int pos = k0; pos < k1; pos++){
    float dot = 0.f;
    #pragma unroll
    for (int d = 0; d < 16; d++) dot += qn[d]*kb[(size_t)(h*16+d)*NK + pos];
    float pp = __expf(dot);
    l += pp;
    #pragma unroll
    for (int d = 0; d < 16; d++)
      acc[d] += pp*kb[(size_t)(128 + h*16+d)*NK + pos];
  }
  l += __shfl_xor(l, 16); l += __shfl_xor(l, 32);
  #pragma unroll
  for (int d = 0; d < 16; d++){
    acc[d] += __shfl_xor(acc[d], 16);
    acc[d] += __shfl_xor(acc[d], 32);
  }
  if ((t >> 4) == 0){
    size_t idx = (size_t)((((bb*8 + h)*16 + q)*S) + s)*18;
    part[idx] = l;
    #pragma unroll
    for (int d = 0; d < 16; d++) part[idx+1+d] = acc[d];
  }
}

__global__ void latcomb_k(const float* __restrict__ part, float* __restrict__ latr, int S){
  int i = blockIdx.x*blockDim.x + threadIdx.x;   // 4096 total
  int d = i & 15, q = (i >> 4) & 15, h = (i >> 8) & 7, bb = i >> 11;
  size_t base = (size_t)(((bb*8 + h)*16 + q)*S)*18;
  float L = 0.f, a = 0.f;
  for (int s = 0; s < S; s++){
    const float* ps = part + base + (size_t)s*18;
    L += ps[0];
    a += ps[1+d];
  }
  latr[(size_t)bb*2048 + (size_t)(h*16+d)*16 + q] = a / fmaxf(L, 1e-30f);
}

extern "C" void kernel_launch(void* const* d_in, const int* in_sizes, int n_in,
                              void* d_out, int out_size, void* d_ws, size_t ws_size,
                              hipStream_t stream){
  const int B = 2, C = 128, HW = 2304;
  const void* x_in        = d_in[0];
  const void* g1          = d_in[1];
  const void* b1          = d_in[2];
  const void* loc_qkv_w   = d_in[3];
  const void* loc_proj_w  = d_in[4];
  const void* loc_proj_b  = d_in[5];
  const void* glob_qkv_w  = d_in[6];
  const void* glob_proj_w = d_in[7];
  const void* glob_proj_b = d_in[8];
  const void* fuse_w1     = d_in[9];
  const void* fuse_b1     = d_in[10];
  const void* fuse_w2     = d_in[11];
  const void* fuse_b2     = d_in[12];
  const void* glat        = d_in[13];
  const void* blat        = d_in[14];
  const void* latents     = d_in[15];
  const void* qlat_w      = d_in[16];
  const void* kvx_w       = d_in[17];
  const void* qx_w        = d_in[18];
  const void* kvlat_w     = d_in[19];
  const void* lat_proj_w  = d_in[20];
  const void* lat_proj_b  = d_in[21];
  const void* g2          = d_in[22];
  const void* b2          = d_in[23];
  const void* ffn_w1      = d_in[24];
  const void* ffn_b1      = d_in[25];
  const void* ffn_w2      = d_in[26];
  const void* ffn_b2      = d_in[27];

  // ---- workspace layout VERBATIM (R8..R18) ----
  float* ws = (float*)d_ws;
  float* P  = ws + 0;
  float* N  = ws + 589824;
  float* A  = ws + 1179648;
  float* Q  = ws + 1769472;

  float* qkv   = Q;                 // 1,769,472
  float* L     = Q + 1769472;       // 589,824
  float* qkvc  = Q + 36864;
  float* gatt  = Q + 147456;
  float* gproj = Q + 184320;
  float* kvx   = Q;                 // 1,179,648
  float* qlat  = Q + 1181696;
  float* latr  = Q + 1185792;
  float* part  = Q + 1198080;       // 663,552 (S=144) — fits below ws+4,128,768
  float* ffh   = Q;                 // 2,359,296

  dim3 blk(256);
  dim3 blk512(512);

  cvt_k<<<2304, blk, 0, stream>>>(x_in, P, 589824);

  // ---- BioAttentionFusion branch ----
  ln2dw_k<<<dim3(144,B), blk, 0, stream>>>(P, g1, b1, N, C, HW, x_in);
  convmfma_k<<<dim3(144,6,B), blk, 0, stream>>>(N,(long)C*HW,C, nullptr,0,0, loc_qkv_w,nullptr,nullptr, qkv,0,384,HW,0, 128,256, 0,nullptr,nullptr, 0,0, nullptr,nullptr,0,0, x_in);
  flat_mfma_k<<<dim3(36,8,B), blk512, 0, stream>>>(qkv,(long)384*HW,0, qkv,(long)384*HW,128,256, A,(long)C*HW, HW,HW,0.25f);
  convmfma_k<<<dim3(144,2,B), blk, 0, stream>>>(A,(long)C*HW,C, nullptr,0,0, loc_proj_w,loc_proj_b,nullptr, L,0,C,HW,0, 0,0, 0,nullptr,nullptr, 0,0, nullptr,nullptr,0,0, x_in);
  // pooled global qkv: pool4 + conv + normk fused
  convmfma_k<<<dim3(9,6,B), blk, 0, stream>>>(N,(long)C*HW,C, nullptr,0,0, glob_qkv_w,nullptr,nullptr, qkvc,0,384,144,0, 128,256, 0,nullptr,nullptr, 1,0, nullptr,nullptr,0,0, x_in);
  attn4_k<<<dim3(3,8,B), blk, 0, stream>>>(qkvc,(long)384*144,0, qkvc,(long)384*144,128,256, gatt,(long)C*144, 144,144,0.25f);
  convmfma_k<<<dim3(9,2,B), blk, 0, stream>>>(gatt,(long)C*144,C, nullptr,0,0, glob_proj_w,glob_proj_b,nullptr, gproj,0,C,144,0, 0,0, 0,nullptr,nullptr, 0,0, nullptr,nullptr,0,0, x_in);
  // fuse1: in2 = gproj with inline bilinear upsample
  convmfma_k<<<dim3(144,2,B), blk, 0, stream>>>(L,(long)C*HW,C, gproj,(long)C*144,C, fuse_w1,fuse_b1,nullptr, N,0,C,HW,1, 0,0, 0,nullptr,nullptr, 0,1, nullptr,nullptr,0,0, x_in);
  convmfma_k<<<dim3(144,2,B), blk, 0, stream>>>(N,(long)C*HW,C, nullptr,0,0, fuse_w2,fuse_b2,P, P,0,C,HW,0, 0,0, 0,nullptr,nullptr, 0,0, nullptr,nullptr,0,0, x_in);

  // ---- LatentMixer branch (LN fused; kvx+qx merged via osplit) ----
  convmfma_k<<<dim3(144,6,B), blk, 0, stream>>>(P,(long)C*HW,C, nullptr,0,0, kvx_w,nullptr,nullptr, kvx,0,256,HW,0, 0,128, 1,glat,blat, 0,0, qx_w,A,128,256, x_in);
  qlat_k<<<16, blk, 0, stream>>>(latents, qlat_w, qlat, x_in);
  latpart_k<<<dim3(144,8,B), 64, 0, stream>>>(qlat, kvx, (long)256*HW, part, HW, 144);
  latcomb_k<<<16, blk, 0, stream>>>(part, latr, 144);
  attn4lat_k<<<dim3(36,8,B), blk, 0, stream>>>(A,(long)C*HW, latr, kvlat_w, N,(long)C*HW, HW, 0.25f, x_in);   // N = xw
  convmfma_k<<<dim3(144,2,B), blk, 0, stream>>>(N,(long)C*HW,C, nullptr,0,0, lat_proj_w,lat_proj_b,P, P,0,C,HW,0, 0,0, 0,nullptr,nullptr, 0,0, nullptr,nullptr,0,0, x_in); // P = x2

  // ---- FFN branch (LN fused into ffn1) ----
  convmfma_k<<<dim3(144,8,B), blk, 0, stream>>>(P,(long)C*HW,C, nullptr,0,0, ffn_w1,ffn_b1,nullptr, ffh,0,512,HW,1, 0,0, 1,g2,b2, 0,0, nullptr,nullptr,0,0, x_in);
  convmfma_k<<<dim3(144,2,B), blk, 0, stream>>>(ffh,(long)512*HW,512, nullptr,0,0, ffn_w2,ffn_b2,P, d_out,1,C,HW,0, 0,0, 0,nullptr,nullptr, 0,0, nullptr,nullptr,0,0, x_in);
}

// Round 12
// 436.299 us; speedup vs baseline: 1.0269x; 1.0173x over previous
//
#include <hip/hip_runtime.h>
#include <hip/hip_bf16.h>

typedef __hip_bfloat16 bf16;
typedef _Float16 f16;
typedef _Float16 f16x4 __attribute__((ext_vector_type(4)));
typedef float f32x4 __attribute__((ext_vector_type(4)));

#define HD 16
#define TK 128
#define KP 20

__device__ __forceinline__ float b2f(bf16 v){ return __bfloat162float(v); }
__device__ __forceinline__ float gelu_f(float x){ return 0.5f*x*(1.0f+erff(x*0.70710678118654752f)); }
__device__ __forceinline__ float rdv(const void* p, size_t i, bool bf){
  return bf ? b2f(((const bf16*)p)[i]) : ((const float*)p)[i];
}
__device__ __forceinline__ float4 ld4f(const void* p, size_t i, bool bf){
  if (bf){
    const bf16* q = (const bf16*)p + i;
    return make_float4(b2f(q[0]), b2f(q[1]), b2f(q[2]), b2f(q[3]));
  }
  return *(const float4*)((const float*)p + i);
}

// ---------------- dtype detector (R30: restored as dedicated dispatch. R10's inline
// detect_bf added ~500cyc serial prologue (24 loads + reduce + 2 logf) to EVERY conv wave,
// gating the K-loop W-loads: ffn1 42.8 -> 54us (+26%). One scalar FLAG load is free.) ------
__global__ void detect_k(const void* __restrict__ x, float* __restrict__ flag){
  if (blockIdx.x != 0) return;
  int l = threadIdx.x;
  const float* xf = (const float*)x;
  const bf16*  xb = (const bf16*)x;
  float sF = 0.f, sB = 0.f;
  for (int i = l; i < 512; i += 64){ float v = fabsf(xf[i]);      if (!(v < 1e30f)) v = 1e30f; sF += v; }
  for (int i = l; i < 1024; i += 64){ float v = fabsf(b2f(xb[i])); if (!(v < 1e30f)) v = 1e30f; sB += v; }
  #pragma unroll
  for (int o = 32; o; o >>= 1){ sF += __shfl_xor(sF, o); sB += __shfl_xor(sB, o); }
  if (l == 0){
    float mF = sF/512.f, mB = sB/1024.f;
    float dF = fabsf(logf(fmaxf(mF, 1e-30f)));
    float dB = fabsf(logf(fmaxf(mB, 1e-30f)));
    *flag = (dB <= dF) ? 1.0f : 0.0f;
  }
}

// ---------------- input -> fp32 convert ----------------
__global__ void cvt_k(const void* __restrict__ in, float* __restrict__ out, int n,
                      const float* __restrict__ flagp){
  bool bf = *flagp > 0.5f;
  int i = blockIdx.x*blockDim.x + threadIdx.x;
  if (i < n) out[i] = rdv(in, i, bf);
}

// ---------------- wave-split LayerNorm (branch1 only) ----------------
__global__ __launch_bounds__(256) void ln2dw_k(
    const float* __restrict__ x, const void* __restrict__ g,
    const void* __restrict__ b, float* __restrict__ y,
    int C, int HW, const float* __restrict__ flagp)
{
  __shared__ float redS[16][16];
  __shared__ float redQ[16][16];
  bool bf = *flagp > 0.5f;
  int t = threadIdx.x, pix = t & 15, sub = t >> 4;
  int p  = blockIdx.x*16 + pix;
  int bb = blockIdx.y;
  const float* xb = x + (size_t)bb*C*HW + p;
  float xv[8];
  float s = 0.f, s2 = 0.f;
  #pragma unroll
  for (int i = 0; i < 8; i++){
    float v = xb[(size_t)(sub*8 + i)*HW];
    xv[i] = v; s += v; s2 += v*v;
  }
  redS[sub][pix] = s; redQ[sub][pix] = s2;
  __syncthreads();
  float st = 0.f, qt = 0.f;
  #pragma unroll
  for (int j = 0; j < 16; j++){ st += redS[j][pix]; qt += redQ[j][pix]; }
  float mu  = st / (float)C;
  float var = fmaxf(qt / (float)C - mu*mu, 0.f);
  float inv = rsqrtf(var + 1e-5f);
  float* yb = y + (size_t)bb*C*HW + p;
  #pragma unroll
  for (int i = 0; i < 8; i++){
    int c = sub*8 + i;
    yb[(size_t)c*HW] = (xv[i] - mu)*inv*rdv(g, c, bf) + rdv(b, c, bf);
  }
}

// ---------------- qlat conv (dedicated; proven R29) ----------------
__global__ __launch_bounds__(256) void qlat_k(
    const void* __restrict__ lat, const void* __restrict__ qw,
    float* __restrict__ qlat, const float* __restrict__ flagp)
{
  bool bf = *flagp > 0.5f;
  int hb = blockIdx.x;           // 16 = (bb*8 + h)
  int bb = hb >> 3, h = hb & 7;
  int t = threadIdx.x;           // 256 = 16d x 16q
  int d = t >> 4, q = t & 15;
  float a = 0.f;
  for (int c = 0; c < 128; c++)
    a += rdv(qw, (size_t)(h*16 + d)*128 + c, bf) * rdv(lat, (size_t)c*16 + q, bf);
  qlat[(size_t)bb*2048 + (size_t)(h*16 + d)*16 + q] = a;
}

// ---------------- MFMA 1x1-conv GEMM (R27 4-wave; R28 osplit; FLAG-based dtype) ----------------
__global__ __launch_bounds__(256) void convmfma_k(
    const float* __restrict__ in1, long in1_bs, int C1,
    const float* __restrict__ in2, long in2_bs, int C2,
    const void* __restrict__ w, const void* __restrict__ bias,
    const float* __restrict__ res, void* __restrict__ out, int to_out,
    int O, int NP, int act, int nlo, int nhi,
    int lnf, const void* __restrict__ lng, const void* __restrict__ lnb,
    int pool, int ups2,
    const void* __restrict__ w2, void* __restrict__ out2, int O2, int osplit,
    const float* __restrict__ flagp)
{
  bool bf = *flagp > 0.5f;
  int lane = threadIdx.x & 63, wv = threadIdx.x >> 6;
  int lm = lane & 15, lg = (lane >> 4) & 3;
  int p0 = blockIdx.x*16, o0 = blockIdx.y*64 + wv*16, bb = blockIdx.z;
  int CW = C1 + C2;
  const void* wu = w; void* outu = out; int Ou = O; int od = 0;
  if (osplit > 0 && o0 >= osplit){ wu = w2; outu = out2; Ou = O2; od = osplit; }
  const float* x1 = in1 + (size_t)bb*in1_bs + p0 + lm;
  const float* x2b = in2 ? (in2 + (size_t)bb*in2_bs) : nullptr;
  float fh = 0.f, fw = 0.f; int i00=0, i01=0, i10=0, i11=0;
  if (ups2){
    int p = p0 + lm; int hh = p/48, ww = p%48;
    float sh = hh*0.25f - 0.375f, sw = ww*0.25f - 0.375f;
    float fh0 = floorf(sh), fw0 = floorf(sw);
    fh = sh - fh0; fw = sw - fw0;
    int h0 = (int)fh0, w0 = (int)fw0;
    int h0c = min(11, max(0, h0)), h1c = min(11, max(0, h0+1));
    int w0c = min(11, max(0, w0)), w1c = min(11, max(0, w0+1));
    i00 = h0c*12 + w0c; i01 = h0c*12 + w1c; i10 = h1c*12 + w0c; i11 = h1c*12 + w1c;
  }
  const float* pN = nullptr;
  if (pool){
    int pc = p0 + lm; int hc = pc/12, wc = pc%12;
    pN = in1 + (size_t)bb*in1_bs + hc*192 + wc*4;
  }
  float mu = 0.f, linv = 0.f;
  if (lnf){
    float s = 0.f, s2 = 0.f;
    for (int c = lg; c < CW; c += 4){ float v = x1[(size_t)c*NP]; s += v; s2 += v*v; }
    s  += __shfl_xor(s, 16);  s  += __shfl_xor(s, 32);
    s2 += __shfl_xor(s2, 16); s2 += __shfl_xor(s2, 32);
    mu = s / (float)CW;
    float var = fmaxf(s2/(float)CW - mu*mu, 0.f);
    linv = rsqrtf(var + 1e-5f);
  }
  f32x4 d; d[0]=0.f; d[1]=0.f; d[2]=0.f; d[3]=0.f;
  #pragma unroll 4
  for (int kc = 0; kc < CW; kc += 16){
    f16x4 xb;
    #pragma unroll
    for (int i = 0; i < 4; i++){
      int c = kc + lg*4 + i;
      float v;
      if (pool){
        const float* s = pN + (size_t)c*2304;
        float a = 0.f;
        #pragma unroll
        for (int r = 0; r < 4; r++)
          #pragma unroll
          for (int cc = 0; cc < 4; cc++) a += s[r*48 + cc];
        v = a * 0.0625f;
      } else if (c < C1){
        v = x1[(size_t)c*NP];
        if (lnf) v = (v - mu)*linv*rdv(lng, c, bf) + rdv(lnb, c, bf);
      } else {
        int c2 = c - C1;
        if (ups2){
          const float* s = x2b + (size_t)c2*144;
          v = (1.f-fh)*((1.f-fw)*s[i00] + fw*s[i01]) + fh*((1.f-fw)*s[i10] + fw*s[i11]);
        } else {
          v = x2b[(size_t)c2*NP + p0 + lm];
        }
      }
      xb[i] = (f16)v;
    }
    float4 wv4 = ld4f(wu, (size_t)(o0 - od + lm)*CW + kc + lg*4, bf);
    f16x4 wa; wa[0]=(f16)wv4.x; wa[1]=(f16)wv4.y; wa[2]=(f16)wv4.z; wa[3]=(f16)wv4.w;
    d = __builtin_amdgcn_mfma_f32_16x16x16f16(wa, xb, d, 0, 0, 0);
  }
  if (o0 >= nlo && o0 < nhi){
    float ss = d[0]*d[0] + d[1]*d[1] + d[2]*d[2] + d[3]*d[3];
    ss += __shfl_xor(ss, 16); ss += __shfl_xor(ss, 32);
    float iv = 1.f / fmaxf(sqrtf(ss), 1e-12f);
    d[0]*=iv; d[1]*=iv; d[2]*=iv; d[3]*=iv;
  }
  #pragma unroll
  for (int r = 0; r < 4; r++){
    int o = o0 - od + lg*4 + r;
    float v = d[r] + (bias ? rdv(bias, o, bf) : 0.f);
    if (act == 1) v = gelu_f(v);
    size_t oi = ((size_t)bb*Ou + o)*NP + p0 + lm;
    if (res) v += res[oi];
    if (to_out && bf) ((bf16*)outu)[oi] = __float2bfloat16(v);
    else              ((float*)outu)[oi] = v;
  }
}

// ---------------- MFMA flash cosine attention (local attn, d=16; proven R22) ----------------
__global__ __launch_bounds__(512) void flat_mfma_k(
    const float* __restrict__ Q, long qbs, int qoff,
    const float* __restrict__ KV, long kbs, int koff, int voff,
    float* __restrict__ Out, long obs, int NQ, int NK, float scale)
{
  __shared__ float OS[8*4*16*17];
  __shared__ float LS[8*4*16];
  int t = threadIdx.x, lane = t & 63, wv = t >> 6;
  int h = blockIdx.y, bb = blockIdx.z;
  int qb = blockIdx.x*64;
  int lm = lane & 15, lg = lane >> 4;
  const float* qp  = Q  + (size_t)bb*qbs;
  const float* kvb = KV + (size_t)bb*kbs;
  f16x4 qf[4];
  #pragma unroll
  for (int qt = 0; qt < 4; qt++){
    float qv[4]; float ss = 0.f;
    #pragma unroll
    for (int i = 0; i < 4; i++){
      qv[i] = qp[(size_t)(qoff + h*16 + lg*4 + i)*NQ + qb + qt*16 + lm];
      ss += qv[i]*qv[i];
    }
    ss += __shfl_xor(ss, 16); ss += __shfl_xor(ss, 32);
    float inv = scale / fmaxf(sqrtf(ss), 1e-12f);
    #pragma unroll
    for (int i = 0; i < 4; i++) qf[qt][i] = (f16)(qv[i]*inv);
  }
  f32x4 of[4];
  float ls[4];
  #pragma unroll
  for (int qt = 0; qt < 4; qt++){
    of[qt][0]=0.f; of[qt][1]=0.f; of[qt][2]=0.f; of[qt][3]=0.f; ls[qt]=0.f;
  }
  int chunk = NK >> 3;
  int p0 = wv*chunk, p1 = p0 + chunk;
  const float* kc = kvb + (size_t)(koff + h*16)*NK;
  const float* vc = kvb + (size_t)(voff + h*16)*NK;
  for (int pos = p0; pos < p1; pos += 16){
    f16x4 kf;
    #pragma unroll
    for (int i = 0; i < 4; i++)
      kf[i] = (f16)kc[(size_t)(lg*4 + i)*NK + pos + lm];
    float4 vvv = *(const float4*)&vc[(size_t)lm*NK + pos + lg*4];
    f16x4 vf; vf[0]=(f16)vvv.x; vf[1]=(f16)vvv.y; vf[2]=(f16)vvv.z; vf[3]=(f16)vvv.w;
    #pragma unroll
    for (int qt = 0; qt < 4; qt++){
      f32x4 s; s[0]=0.f; s[1]=0.f; s[2]=0.f; s[3]=0.f;
      s = __builtin_amdgcn_mfma_f32_16x16x16f16(kf, qf[qt], s, 0, 0, 0);
      f16x4 pf;
      #pragma unroll
      for (int r = 0; r < 4; r++){
        float pp = __expf(s[r]);
        ls[qt] += pp;
        pf[r] = (f16)pp;
      }
      of[qt] = __builtin_amdgcn_mfma_f32_16x16x16f16(vf, pf, of[qt], 0, 0, 0);
    }
  }
  #pragma unroll
  for (int qt = 0; qt < 4; qt++){
    ls[qt] += __shfl_xor(ls[qt], 16);
    ls[qt] += __shfl_xor(ls[qt], 32);
    #pragma unroll
    for (int r = 0; r < 4; r++)
      OS[((wv*4 + qt)*16 + lm)*17 + lg*4 + r] = of[qt][r];
    if (lg == 0) LS[(wv*4 + qt)*16 + lm] = ls[qt];
  }
  __syncthreads();
  #pragma unroll
  for (int rep = 0; rep < 2; rep++){
    int o = t + rep*512;
    int d = o >> 6, qq = o & 63;
    int qt = qq >> 4, q = qq & 15;
    float acc = 0.f, lsum = 0.f;
    #pragma unroll
    for (int w = 0; w < 8; w++){
      acc  += OS[((w*4 + qt)*16 + q)*17 + d];
      lsum += LS[(w*4 + qt)*16 + q];
    }
    Out[(size_t)bb*obs + (size_t)(h*16 + d)*NQ + qb + qq] = acc / fmaxf(lsum, 1e-30f);
  }
}

// ---------------- attn4, no-max (global attn NK=144; proven) ----------------
__global__ __launch_bounds__(256) void attn4_k(
    const float* __restrict__ Q, long qbs, int qoff,
    const float* __restrict__ KV, long kbs, int koff, int voff,
    float* __restrict__ Out, long obs, int NQ, int NK, float scale)
{
  __shared__ __align__(16) float Ks[TK*KP];
  __shared__ __align__(16) float Vs[TK*KP];
  int tid = threadIdx.x;
  int sub = tid & 3;
  int h = blockIdx.y, bb = blockIdx.z;
  int qi = blockIdx.x*64 + (tid >> 2);
  bool qv = qi < NQ;
  float qn[4] = {0,0,0,0}, acc[4] = {0,0,0,0};
  float l = 0.f;
  if (qv){
    float s = 0.f;
    #pragma unroll
    for (int j = 0; j < 4; j++){
      qn[j] = Q[(size_t)bb*qbs + (size_t)(qoff + h*16 + sub*4 + j)*NQ + qi];
      s += qn[j]*qn[j];
    }
    s += __shfl_xor(s, 1); s += __shfl_xor(s, 2);
    float inv = scale / fmaxf(sqrtf(s), 1e-12f);
    #pragma unroll
    for (int j = 0; j < 4; j++) qn[j] *= inv;
  }
  for (int k0 = 0; k0 < NK; k0 += TK){
    int lim = min(TK, NK - k0);
    for (int i = tid; i < 16*TK; i += 256){
      int pos = i & (TK-1), d = i >> 7;
      if (pos < lim){
        Ks[pos*KP + d] = KV[(size_t)bb*kbs + (size_t)(koff + h*16 + d)*NK + k0 + pos];
        Vs[pos*KP + d] = KV[(size_t)bb*kbs + (size_t)(voff + h*16 + d)*NK + k0 + pos];
      }
    }
    __syncthreads();
    for (int pos = 0; pos < lim; pos++){
      float4 k4 = *(const float4*)&Ks[pos*KP + sub*4];
      float dd = qn[0]*k4.x + qn[1]*k4.y + qn[2]*k4.z + qn[3]*k4.w;
      dd += __shfl_xor(dd, 1); dd += __shfl_xor(dd, 2);
      float pp = __expf(dd);
      l += pp;
      float4 v4 = *(const float4*)&Vs[pos*KP + sub*4];
      acc[0] += pp*v4.x;
      acc[1] += pp*v4.y;
      acc[2] += pp*v4.z;
      acc[3] += pp*v4.w;
    }
    __syncthreads();
  }
  if (qv){
    float li = 1.f / fmaxf(l, 1e-30f);
    #pragma unroll
    for (int j = 0; j < 4; j++)
      Out[(size_t)bb*obs + (size_t)(h*16 + sub*4 + j)*NQ + qi] = acc[j]*li;
  }
}

// ---------------- xw attention with INLINE kvlat conv + K-norm (proven R28) ----------------
__global__ __launch_bounds__(256) void attn4lat_k(
    const float* __restrict__ Q, long qbs,
    const float* __restrict__ latr, const void* __restrict__ kvw,
    float* __restrict__ Out, long obs, int NQ, float scale,
    const float* __restrict__ flagp)
{
  __shared__ __align__(16) float Ks[16*KP];
  __shared__ __align__(16) float Vs[16*KP];
  bool bf = *flagp > 0.5f;
  int tid = threadIdx.x;
  int h = blockIdx.y, bb = blockIdx.z;
  {
    int pos = tid & 15, d = tid >> 4;
    const float* lr = latr + (size_t)bb*2048;
    float kk = 0.f, vv = 0.f;
    for (int c = 0; c < 128; c++){
      float xv = lr[(size_t)c*16 + pos];
      kk += rdv(kvw, (size_t)(h*16 + d)*128 + c, bf) * xv;
      vv += rdv(kvw, (size_t)(128 + h*16 + d)*128 + c, bf) * xv;
    }
    Ks[pos*KP + d] = kk;
    Vs[pos*KP + d] = vv;
  }
  __syncthreads();
  if (tid < 16){
    float ss = 0.f;
    #pragma unroll
    for (int d = 0; d < 16; d++){ float v = Ks[tid*KP + d]; ss += v*v; }
    float iv = 1.f / fmaxf(sqrtf(ss), 1e-12f);
    #pragma unroll
    for (int d = 0; d < 16; d++) Ks[tid*KP + d] *= iv;
  }
  __syncthreads();
  int sub = tid & 3;
  int qi = blockIdx.x*64 + (tid >> 2);
  float qn[4]; float acc[4] = {0,0,0,0}; float l = 0.f;
  {
    float s = 0.f;
    #pragma unroll
    for (int j = 0; j < 4; j++){
      qn[j] = Q[(size_t)bb*qbs + (size_t)(h*16 + sub*4 + j)*NQ + qi];
      s += qn[j]*qn[j];
    }
    s += __shfl_xor(s, 1); s += __shfl_xor(s, 2);
    float inv = scale / fmaxf(sqrtf(s), 1e-12f);
    #pragma unroll
    for (int j = 0; j < 4; j++) qn[j] *= inv;
  }
  for (int pos = 0; pos < 16; pos++){
    float4 k4 = *(const float4*)&Ks[pos*KP + sub*4];
    float dd = qn[0]*k4.x + qn[1]*k4.y + qn[2]*k4.z + qn[3]*k4.w;
    dd += __shfl_xor(dd, 1); dd += __shfl_xor(dd, 2);
    float pp = __expf(dd);
    l += pp;
    float4 v4 = *(const float4*)&Vs[pos*KP + sub*4];
    acc[0] += pp*v4.x;
    acc[1] += pp*v4.y;
    acc[2] += pp*v4.z;
    acc[3] += pp*v4.w;
  }
  float li = 1.f / fmaxf(l, 1e-30f);
  #pragma unroll
  for (int j = 0; j < 4; j++)
    Out[(size_t)bb*obs + (size_t)(h*16 + sub*4 + j)*NQ + qi] = acc[j]*li;
}

// ---------------- latent-read attention, split-K partials (S=144, proven R29) ----------------
__global__ void latpart_k(const float* __restrict__ ql, const float* __restrict__ kvx,
                          long kbs, float* __restrict__ part, int NK, int S){
  int s = blockIdx.x, h = blockIdx.y, bb = blockIdx.z;
  int t = threadIdx.x;
  int q = t & 15, sub = (t >> 4) & 3;
  float qn[16]; float ss = 0.f;
  #pragma unroll
  for (int d = 0; d < 16; d++){
    qn[d] = ql[(size_t)bb*2048 + (size_t)(h*16+d)*16 + q];
    ss += qn[d]*qn[d];
  }
  float inv = 0.25f / fmaxf(sqrtf(ss), 1e-12f);
  #pragma unroll
  for (int d = 0; d < 16; d++) qn[d] *= inv;
  float l = 0.f, acc[16];
  #pragma unroll
  for (int d = 0; d < 16; d++) acc[d] = 0.f;
  int chunk = NK / S, c4 = chunk >> 2;
  int k0 = s*chunk + sub*c4, k1 = k0 + c4;
  const float* kb = kvx + (size_t)bb*kbs;
  for (int pos = k0; pos < k1; pos++){
    float dot = 0.f;
    #pragma unroll
    for (int d = 0; d < 16; d++) dot += qn[d]*kb[(size_t)(h*16+d)*NK + pos];
    float pp = __expf(dot);
    l += pp;
    #pragma unroll
    for (int d = 0; d < 16; d++)
      acc[d] += pp*kb[(size_t)(128 + h*16+d)*NK + pos];
  }
  l += __shfl_xor(l, 16); l += __shfl_xor(l, 32);
  #pragma unroll
  for (int d = 0; d < 16; d++){
    acc[d] += __shfl_xor(acc[d], 16);
    acc[d] += __shfl_xor(acc[d], 32);
  }
  if ((t >> 4) == 0){
    size_t idx = (size_t)((((bb*8 + h)*16 + q)*S) + s)*18;
    part[idx] = l;
    #pragma unroll
    for (int d = 0; d < 16; d++) part[idx+1+d] = acc[d];
  }
}

__global__ void latcomb_k(const float* __restrict__ part, float* __restrict__ latr, int S){
  int i = blockIdx.x*blockDim.x + threadIdx.x;   // 4096 total
  int d = i & 15, q = (i >> 4) & 15, h = (i >> 8) & 7, bb = i >> 11;
  size_t base = (size_t)(((bb*8 + h)*16 + q)*S)*18;
  float L = 0.f, a = 0.f;
  for (int s = 0; s < S; s++){
    const float* ps = part + base + (size_t)s*18;
    L += ps[0];
    a += ps[1+d];
  }
  latr[(size_t)bb*2048 + (size_t)(h*16+d)*16 + q] = a / fmaxf(L, 1e-30f);
}

extern "C" void kernel_launch(void* const* d_in, const int* in_sizes, int n_in,
                              void* d_out, int out_size, void* d_ws, size_t ws_size,
                              hipStream_t stream){
  const int B = 2, C = 128, HW = 2304;
  const void* x_in        = d_in[0];
  const void* g1          = d_in[1];
  const void* b1          = d_in[2];
  const void* loc_qkv_w   = d_in[3];
  const void* loc_proj_w  = d_in[4];
  const void* loc_proj_b  = d_in[5];
  const void* glob_qkv_w  = d_in[6];
  const void* glob_proj_w = d_in[7];
  const void* glob_proj_b = d_in[8];
  const void* fuse_w1     = d_in[9];
  const void* fuse_b1     = d_in[10];
  const void* fuse_w2     = d_in[11];
  const void* fuse_b2     = d_in[12];
  const void* glat        = d_in[13];
  const void* blat        = d_in[14];
  const void* latents     = d_in[15];
  const void* qlat_w      = d_in[16];
  const void* kvx_w       = d_in[17];
  const void* qx_w        = d_in[18];
  const void* kvlat_w     = d_in[19];
  const void* lat_proj_w  = d_in[20];
  const void* lat_proj_b  = d_in[21];
  const void* g2          = d_in[22];
  const void* b2          = d_in[23];
  const void* ffn_w1      = d_in[24];
  const void* ffn_b1      = d_in[25];
  const void* ffn_w2      = d_in[26];
  const void* ffn_b2      = d_in[27];

  // ---- workspace layout VERBATIM (R8..R18) ----
  float* ws = (float*)d_ws;
  float* P  = ws + 0;
  float* N  = ws + 589824;
  float* A  = ws + 1179648;
  float* Q  = ws + 1769472;
  float* FLAG = ws + 4128768;

  float* qkv   = Q;                 // 1,769,472
  float* L     = Q + 1769472;       // 589,824
  float* qkvc  = Q + 36864;
  float* gatt  = Q + 147456;
  float* gproj = Q + 184320;
  float* kvx   = Q;                 // 1,179,648
  float* qlat  = Q + 1181696;
  float* latr  = Q + 1185792;
  float* part  = Q + 1198080;       // 663,552 (S=144) — fits below ws+4,128,768
  float* ffh   = Q;                 // 2,359,296

  dim3 blk(256);
  dim3 blk512(512);

  detect_k<<<1, 64, 0, stream>>>(x_in, FLAG);
  cvt_k<<<2304, blk, 0, stream>>>(x_in, P, 589824, FLAG);

  // ---- BioAttentionFusion branch ----
  ln2dw_k<<<dim3(144,B), blk, 0, stream>>>(P, g1, b1, N, C, HW, FLAG);
  convmfma_k<<<dim3(144,6,B), blk, 0, stream>>>(N,(long)C*HW,C, nullptr,0,0, loc_qkv_w,nullptr,nullptr, qkv,0,384,HW,0, 128,256, 0,nullptr,nullptr, 0,0, nullptr,nullptr,0,0, FLAG);
  flat_mfma_k<<<dim3(36,8,B), blk512, 0, stream>>>(qkv,(long)384*HW,0, qkv,(long)384*HW,128,256, A,(long)C*HW, HW,HW,0.25f);
  convmfma_k<<<dim3(144,2,B), blk, 0, stream>>>(A,(long)C*HW,C, nullptr,0,0, loc_proj_w,loc_proj_b,nullptr, L,0,C,HW,0, 0,0, 0,nullptr,nullptr, 0,0, nullptr,nullptr,0,0, FLAG);
  // pooled global qkv: pool4 + conv + normk fused
  convmfma_k<<<dim3(9,6,B), blk, 0, stream>>>(N,(long)C*HW,C, nullptr,0,0, glob_qkv_w,nullptr,nullptr, qkvc,0,384,144,0, 128,256, 0,nullptr,nullptr, 1,0, nullptr,nullptr,0,0, FLAG);
  attn4_k<<<dim3(3,8,B), blk, 0, stream>>>(qkvc,(long)384*144,0, qkvc,(long)384*144,128,256, gatt,(long)C*144, 144,144,0.25f);
  convmfma_k<<<dim3(9,2,B), blk, 0, stream>>>(gatt,(long)C*144,C, nullptr,0,0, glob_proj_w,glob_proj_b,nullptr, gproj,0,C,144,0, 0,0, 0,nullptr,nullptr, 0,0, nullptr,nullptr,0,0, FLAG);
  // fuse1: in2 = gproj with inline bilinear upsample
  convmfma_k<<<dim3(144,2,B), blk, 0, stream>>>(L,(long)C*HW,C, gproj,(long)C*144,C, fuse_w1,fuse_b1,nullptr, N,0,C,HW,1, 0,0, 0,nullptr,nullptr, 0,1, nullptr,nullptr,0,0, FLAG);
  convmfma_k<<<dim3(144,2,B), blk, 0, stream>>>(N,(long)C*HW,C, nullptr,0,0, fuse_w2,fuse_b2,P, P,0,C,HW,0, 0,0, 0,nullptr,nullptr, 0,0, nullptr,nullptr,0,0, FLAG);

  // ---- LatentMixer branch (LN fused; kvx+qx merged via osplit) ----
  convmfma_k<<<dim3(144,6,B), blk, 0, stream>>>(P,(long)C*HW,C, nullptr,0,0, kvx_w,nullptr,nullptr, kvx,0,256,HW,0, 0,128, 1,glat,blat, 0,0, qx_w,A,128,256, FLAG);
  qlat_k<<<16, blk, 0, stream>>>(latents, qlat_w, qlat, FLAG);
  latpart_k<<<dim3(144,8,B), 64, 0, stream>>>(qlat, kvx, (long)256*HW, part, HW, 144);
  latcomb_k<<<16, blk, 0, stream>>>(part, latr, 144);
  attn4lat_k<<<dim3(36,8,B), blk, 0, stream>>>(A,(long)C*HW, latr, kvlat_w, N,(long)C*HW, HW, 0.25f, FLAG);   // N = xw
  convmfma_k<<<dim3(144,2,B), blk, 0, stream>>>(N,(long)C*HW,C, nullptr,0,0, lat_proj_w,lat_proj_b,P, P,0,C,HW,0, 0,0, 0,nullptr,nullptr, 0,0, nullptr,nullptr,0,0, FLAG); // P = x2

  // ---- FFN branch (LN fused into ffn1) ----
  convmfma_k<<<dim3(144,8,B), blk, 0, stream>>>(P,(long)C*HW,C, nullptr,0,0, ffn_w1,ffn_b1,nullptr, ffh,0,512,HW,1, 0,0, 1,g2,b2, 0,0, nullptr,nullptr,0,0, FLAG);
  convmfma_k<<<dim3(144,2,B), blk, 0, stream>>>(ffh,(long)512*HW,512, nullptr,0,0, ffn_w2,ffn_b2,P, d_out,1,C,HW,0, 0,0, 0,nullptr,nullptr, 0,0, nullptr,nullptr,0,0, FLAG);
}

// Round 13
// 418.075 us; speedup vs baseline: 1.0716x; 1.0436x over previous
//
#include <hip/hip_runtime.h>
#include <hip/hip_bf16.h>

typedef __hip_bfloat16 bf16;
typedef _Float16 f16;
typedef _Float16 f16x4 __attribute__((ext_vector_type(4)));
typedef float f32x4 __attribute__((ext_vector_type(4)));

#define HD 16
#define TK 128
#define KP 20

__device__ __forceinline__ float b2f(bf16 v){ return __bfloat162float(v); }
__device__ __forceinline__ float gelu_f(float x){ return 0.5f*x*(1.0f+erff(x*0.70710678118654752f)); }
__device__ __forceinline__ float rdv(const void* p, size_t i, bool bf){
  return bf ? b2f(((const bf16*)p)[i]) : ((const float*)p)[i];
}
__device__ __forceinline__ float4 ld4f(const void* p, size_t i, bool bf){
  if (bf){
    const bf16* q = (const bf16*)p + i;
    return make_float4(b2f(q[0]), b2f(q[1]), b2f(q[2]), b2f(q[3]));
  }
  return *(const float4*)((const float*)p + i);
}

// ---------------- dtype detector (dedicated dispatch; proven R30) ----------------
__global__ void detect_k(const void* __restrict__ x, float* __restrict__ flag){
  if (blockIdx.x != 0) return;
  int l = threadIdx.x;
  const float* xf = (const float*)x;
  const bf16*  xb = (const bf16*)x;
  float sF = 0.f, sB = 0.f;
  for (int i = l; i < 512; i += 64){ float v = fabsf(xf[i]);      if (!(v < 1e30f)) v = 1e30f; sF += v; }
  for (int i = l; i < 1024; i += 64){ float v = fabsf(b2f(xb[i])); if (!(v < 1e30f)) v = 1e30f; sB += v; }
  #pragma unroll
  for (int o = 32; o; o >>= 1){ sF += __shfl_xor(sF, o); sB += __shfl_xor(sB, o); }
  if (l == 0){
    float mF = sF/512.f, mB = sB/1024.f;
    float dF = fabsf(logf(fmaxf(mF, 1e-30f)));
    float dB = fabsf(logf(fmaxf(mB, 1e-30f)));
    *flag = (dB <= dF) ? 1.0f : 0.0f;
  }
}

// ---------------- input -> fp32 convert ----------------
__global__ void cvt_k(const void* __restrict__ in, float* __restrict__ out, int n,
                      const float* __restrict__ flagp){
  bool bf = *flagp > 0.5f;
  int i = blockIdx.x*blockDim.x + threadIdx.x;
  if (i < n) out[i] = rdv(in, i, bf);
}

// ---------------- wave-split LayerNorm (branch1 only) ----------------
__global__ __launch_bounds__(256) void ln2dw_k(
    const float* __restrict__ x, const void* __restrict__ g,
    const void* __restrict__ b, float* __restrict__ y,
    int C, int HW, const float* __restrict__ flagp)
{
  __shared__ float redS[16][16];
  __shared__ float redQ[16][16];
  bool bf = *flagp > 0.5f;
  int t = threadIdx.x, pix = t & 15, sub = t >> 4;
  int p  = blockIdx.x*16 + pix;
  int bb = blockIdx.y;
  const float* xb = x + (size_t)bb*C*HW + p;
  float xv[8];
  float s = 0.f, s2 = 0.f;
  #pragma unroll
  for (int i = 0; i < 8; i++){
    float v = xb[(size_t)(sub*8 + i)*HW];
    xv[i] = v; s += v; s2 += v*v;
  }
  redS[sub][pix] = s; redQ[sub][pix] = s2;
  __syncthreads();
  float st = 0.f, qt = 0.f;
  #pragma unroll
  for (int j = 0; j < 16; j++){ st += redS[j][pix]; qt += redQ[j][pix]; }
  float mu  = st / (float)C;
  float var = fmaxf(qt / (float)C - mu*mu, 0.f);
  float inv = rsqrtf(var + 1e-5f);
  float* yb = y + (size_t)bb*C*HW + p;
  #pragma unroll
  for (int i = 0; i < 8; i++){
    int c = sub*8 + i;
    yb[(size_t)c*HW] = (xv[i] - mu)*inv*rdv(g, c, bf) + rdv(b, c, bf);
  }
}

// ---------------- qlat conv (dedicated; proven R29) ----------------
__global__ __launch_bounds__(256) void qlat_k(
    const void* __restrict__ lat, const void* __restrict__ qw,
    float* __restrict__ qlat, const float* __restrict__ flagp)
{
  bool bf = *flagp > 0.5f;
  int hb = blockIdx.x;           // 16 = (bb*8 + h)
  int bb = hb >> 3, h = hb & 7;
  int t = threadIdx.x;           // 256 = 16d x 16q
  int d = t >> 4, q = t & 15;
  float a = 0.f;
  for (int c = 0; c < 128; c++)
    a += rdv(qw, (size_t)(h*16 + d)*128 + c, bf) * rdv(lat, (size_t)c*16 + q, bf);
  qlat[(size_t)bb*2048 + (size_t)(h*16 + d)*16 + q] = a;
}

// ---------------- MFMA 1x1-conv GEMM (R31: +ot2 dual-o-subtile) ----------------
// ot2=1: each wave computes TWO 16-o subtiles (rows [o0,o0+32)) from ONE X-fragment load
// and ONE inline-LN stats pass — halves X traffic and lnf redundancy for fat convs
// (ffn1 grid.y 8->4, qkv/kvx 6->3). Region boundaries (osplit, nlo/nhi) are %32-aligned
// so subtiles never straddle. ot2=0 path is bit-identical to R12 (proven).
__global__ __launch_bounds__(256) void convmfma_k(
    const float* __restrict__ in1, long in1_bs, int C1,
    const float* __restrict__ in2, long in2_bs, int C2,
    const void* __restrict__ w, const void* __restrict__ bias,
    const float* __restrict__ res, void* __restrict__ out, int to_out,
    int O, int NP, int act, int nlo, int nhi,
    int lnf, const void* __restrict__ lng, const void* __restrict__ lnb,
    int pool, int ups2,
    const void* __restrict__ w2, void* __restrict__ out2, int O2, int osplit,
    int ot2, const float* __restrict__ flagp)
{
  bool bf = *flagp > 0.5f;
  int lane = threadIdx.x & 63, wv = threadIdx.x >> 6;
  int lm = lane & 15, lg = (lane >> 4) & 3;
  int p0 = blockIdx.x*16, bb = blockIdx.z;
  int o0 = ot2 ? (blockIdx.y*128 + wv*32) : (blockIdx.y*64 + wv*16);
  int CW = C1 + C2;
  const void* wu = w; void* outu = out; int Ou = O; int od = 0;
  if (osplit > 0 && o0 >= osplit){ wu = w2; outu = out2; Ou = O2; od = osplit; }
  const float* x1 = in1 + (size_t)bb*in1_bs + p0 + lm;
  const float* x2b = in2 ? (in2 + (size_t)bb*in2_bs) : nullptr;
  float fh = 0.f, fw = 0.f; int i00=0, i01=0, i10=0, i11=0;
  if (ups2){
    int p = p0 + lm; int hh = p/48, ww = p%48;
    float sh = hh*0.25f - 0.375f, sw = ww*0.25f - 0.375f;
    float fh0 = floorf(sh), fw0 = floorf(sw);
    fh = sh - fh0; fw = sw - fw0;
    int h0 = (int)fh0, w0 = (int)fw0;
    int h0c = min(11, max(0, h0)), h1c = min(11, max(0, h0+1));
    int w0c = min(11, max(0, w0)), w1c = min(11, max(0, w0+1));
    i00 = h0c*12 + w0c; i01 = h0c*12 + w1c; i10 = h1c*12 + w0c; i11 = h1c*12 + w1c;
  }
  const float* pN = nullptr;
  if (pool){
    int pc = p0 + lm; int hc = pc/12, wc = pc%12;
    pN = in1 + (size_t)bb*in1_bs + hc*192 + wc*4;
  }
  float mu = 0.f, linv = 0.f;
  if (lnf){
    float s = 0.f, s2 = 0.f;
    for (int c = lg; c < CW; c += 4){ float v = x1[(size_t)c*NP]; s += v; s2 += v*v; }
    s  += __shfl_xor(s, 16);  s  += __shfl_xor(s, 32);
    s2 += __shfl_xor(s2, 16); s2 += __shfl_xor(s2, 32);
    mu = s / (float)CW;
    float var = fmaxf(s2/(float)CW - mu*mu, 0.f);
    linv = rsqrtf(var + 1e-5f);
  }
  f32x4 d0, d1;
  d0[0]=0.f; d0[1]=0.f; d0[2]=0.f; d0[3]=0.f;
  d1[0]=0.f; d1[1]=0.f; d1[2]=0.f; d1[3]=0.f;
  #pragma unroll 4
  for (int kc = 0; kc < CW; kc += 16){
    f16x4 xb;
    #pragma unroll
    for (int i = 0; i < 4; i++){
      int c = kc + lg*4 + i;
      float v;
      if (pool){
        const float* s = pN + (size_t)c*2304;
        float a = 0.f;
        #pragma unroll
        for (int r = 0; r < 4; r++)
          #pragma unroll
          for (int cc = 0; cc < 4; cc++) a += s[r*48 + cc];
        v = a * 0.0625f;
      } else if (c < C1){
        v = x1[(size_t)c*NP];
        if (lnf) v = (v - mu)*linv*rdv(lng, c, bf) + rdv(lnb, c, bf);
      } else {
        int c2 = c - C1;
        if (ups2){
          const float* s = x2b + (size_t)c2*144;
          v = (1.f-fh)*((1.f-fw)*s[i00] + fw*s[i01]) + fh*((1.f-fw)*s[i10] + fw*s[i11]);
        } else {
          v = x2b[(size_t)c2*NP + p0 + lm];
        }
      }
      xb[i] = (f16)v;
    }
    float4 w0v = ld4f(wu, (size_t)(o0 - od + lm)*CW + kc + lg*4, bf);
    f16x4 wa; wa[0]=(f16)w0v.x; wa[1]=(f16)w0v.y; wa[2]=(f16)w0v.z; wa[3]=(f16)w0v.w;
    d0 = __builtin_amdgcn_mfma_f32_16x16x16f16(wa, xb, d0, 0, 0, 0);
    if (ot2){
      float4 w1v = ld4f(wu, (size_t)(o0 + 16 - od + lm)*CW + kc + lg*4, bf);
      f16x4 wb; wb[0]=(f16)w1v.x; wb[1]=(f16)w1v.y; wb[2]=(f16)w1v.z; wb[3]=(f16)w1v.w;
      d1 = __builtin_amdgcn_mfma_f32_16x16x16f16(wb, xb, d1, 0, 0, 0);
    }
  }
  if (o0 >= nlo && o0 < nhi){
    float ss = d0[0]*d0[0] + d0[1]*d0[1] + d0[2]*d0[2] + d0[3]*d0[3];
    ss += __shfl_xor(ss, 16); ss += __shfl_xor(ss, 32);
    float iv = 1.f / fmaxf(sqrtf(ss), 1e-12f);
    d0[0]*=iv; d0[1]*=iv; d0[2]*=iv; d0[3]*=iv;
  }
  if (ot2 && (o0 + 16) >= nlo && (o0 + 16) < nhi){
    float ss = d1[0]*d1[0] + d1[1]*d1[1] + d1[2]*d1[2] + d1[3]*d1[3];
    ss += __shfl_xor(ss, 16); ss += __shfl_xor(ss, 32);
    float iv = 1.f / fmaxf(sqrtf(ss), 1e-12f);
    d1[0]*=iv; d1[1]*=iv; d1[2]*=iv; d1[3]*=iv;
  }
  #pragma unroll
  for (int r = 0; r < 4; r++){
    int o = o0 - od + lg*4 + r;
    float v = d0[r] + (bias ? rdv(bias, o, bf) : 0.f);
    if (act == 1) v = gelu_f(v);
    size_t oi = ((size_t)bb*Ou + o)*NP + p0 + lm;
    if (res) v += res[oi];
    if (to_out && bf) ((bf16*)outu)[oi] = __float2bfloat16(v);
    else              ((float*)outu)[oi] = v;
  }
  if (ot2){
    #pragma unroll
    for (int r = 0; r < 4; r++){
      int o = o0 + 16 - od + lg*4 + r;
      float v = d1[r] + (bias ? rdv(bias, o, bf) : 0.f);
      if (act == 1) v = gelu_f(v);
      size_t oi = ((size_t)bb*Ou + o)*NP + p0 + lm;
      if (res) v += res[oi];
      if (to_out && bf) ((bf16*)outu)[oi] = __float2bfloat16(v);
      else              ((float*)outu)[oi] = v;
    }
  }
}

// ---------------- MFMA flash cosine attention (local attn, d=16; proven R22) ----------------
__global__ __launch_bounds__(512) void flat_mfma_k(
    const float* __restrict__ Q, long qbs, int qoff,
    const float* __restrict__ KV, long kbs, int koff, int voff,
    float* __restrict__ Out, long obs, int NQ, int NK, float scale)
{
  __shared__ float OS[8*4*16*17];
  __shared__ float LS[8*4*16];
  int t = threadIdx.x, lane = t & 63, wv = t >> 6;
  int h = blockIdx.y, bb = blockIdx.z;
  int qb = blockIdx.x*64;
  int lm = lane & 15, lg = lane >> 4;
  const float* qp  = Q  + (size_t)bb*qbs;
  const float* kvb = KV + (size_t)bb*kbs;
  f16x4 qf[4];
  #pragma unroll
  for (int qt = 0; qt < 4; qt++){
    float qv[4]; float ss = 0.f;
    #pragma unroll
    for (int i = 0; i < 4; i++){
      qv[i] = qp[(size_t)(qoff + h*16 + lg*4 + i)*NQ + qb + qt*16 + lm];
      ss += qv[i]*qv[i];
    }
    ss += __shfl_xor(ss, 16); ss += __shfl_xor(ss, 32);
    float inv = scale / fmaxf(sqrtf(ss), 1e-12f);
    #pragma unroll
    for (int i = 0; i < 4; i++) qf[qt][i] = (f16)(qv[i]*inv);
  }
  f32x4 of[4];
  float ls[4];
  #pragma unroll
  for (int qt = 0; qt < 4; qt++){
    of[qt][0]=0.f; of[qt][1]=0.f; of[qt][2]=0.f; of[qt][3]=0.f; ls[qt]=0.f;
  }
  int chunk = NK >> 3;
  int p0 = wv*chunk, p1 = p0 + chunk;
  const float* kc = kvb + (size_t)(koff + h*16)*NK;
  const float* vc = kvb + (size_t)(voff + h*16)*NK;
  for (int pos = p0; pos < p1; pos += 16){
    f16x4 kf;
    #pragma unroll
    for (int i = 0; i < 4; i++)
      kf[i] = (f16)kc[(size_t)(lg*4 + i)*NK + pos + lm];
    float4 vvv = *(const float4*)&vc[(size_t)lm*NK + pos + lg*4];
    f16x4 vf; vf[0]=(f16)vvv.x; vf[1]=(f16)vvv.y; vf[2]=(f16)vvv.z; vf[3]=(f16)vvv.w;
    #pragma unroll
    for (int qt = 0; qt < 4; qt++){
      f32x4 s; s[0]=0.f; s[1]=0.f; s[2]=0.f; s[3]=0.f;
      s = __builtin_amdgcn_mfma_f32_16x16x16f16(kf, qf[qt], s, 0, 0, 0);
      f16x4 pf;
      #pragma unroll
      for (int r = 0; r < 4; r++){
        float pp = __expf(s[r]);
        ls[qt] += pp;
        pf[r] = (f16)pp;
      }
      of[qt] = __builtin_amdgcn_mfma_f32_16x16x16f16(vf, pf, of[qt], 0, 0, 0);
    }
  }
  #pragma unroll
  for (int qt = 0; qt < 4; qt++){
    ls[qt] += __shfl_xor(ls[qt], 16);
    ls[qt] += __shfl_xor(ls[qt], 32);
    #pragma unroll
    for (int r = 0; r < 4; r++)
      OS[((wv*4 + qt)*16 + lm)*17 + lg*4 + r] = of[qt][r];
    if (lg == 0) LS[(wv*4 + qt)*16 + lm] = ls[qt];
  }
  __syncthreads();
  #pragma unroll
  for (int rep = 0; rep < 2; rep++){
    int o = t + rep*512;
    int d = o >> 6, qq = o & 63;
    int qt = qq >> 4, q = qq & 15;
    float acc = 0.f, lsum = 0.f;
    #pragma unroll
    for (int w = 0; w < 8; w++){
      acc  += OS[((w*4 + qt)*16 + q)*17 + d];
      lsum += LS[(w*4 + qt)*16 + q];
    }
    Out[(size_t)bb*obs + (size_t)(h*16 + d)*NQ + qb + qq] = acc / fmaxf(lsum, 1e-30f);
  }
}

// ---------------- attn4, no-max (global attn NK=144; proven) ----------------
__global__ __launch_bounds__(256) void attn4_k(
    const float* __restrict__ Q, long qbs, int qoff,
    const float* __restrict__ KV, long kbs, int koff, int voff,
    float* __restrict__ Out, long obs, int NQ, int NK, float scale)
{
  __shared__ __align__(16) float Ks[TK*KP];
  __shared__ __align__(16) float Vs[TK*KP];
  int tid = threadIdx.x;
  int sub = tid & 3;
  int h = blockIdx.y, bb = blockIdx.z;
  int qi = blockIdx.x*64 + (tid >> 2);
  bool qv = qi < NQ;
  float qn[4] = {0,0,0,0}, acc[4] = {0,0,0,0};
  float l = 0.f;
  if (qv){
    float s = 0.f;
    #pragma unroll
    for (int j = 0; j < 4; j++){
      qn[j] = Q[(size_t)bb*qbs + (size_t)(qoff + h*16 + sub*4 + j)*NQ + qi];
      s += qn[j]*qn[j];
    }
    s += __shfl_xor(s, 1); s += __shfl_xor(s, 2);
    float inv = scale / fmaxf(sqrtf(s), 1e-12f);
    #pragma unroll
    for (int j = 0; j < 4; j++) qn[j] *= inv;
  }
  for (int k0 = 0; k0 < NK; k0 += TK){
    int lim = min(TK, NK - k0);
    for (int i = tid; i < 16*TK; i += 256){
      int pos = i & (TK-1), d = i >> 7;
      if (pos < lim){
        Ks[pos*KP + d] = KV[(size_t)bb*kbs + (size_t)(koff + h*16 + d)*NK + k0 + pos];
        Vs[pos*KP + d] = KV[(size_t)bb*kbs + (size_t)(voff + h*16 + d)*NK + k0 + pos];
      }
    }
    __syncthreads();
    for (int pos = 0; pos < lim; pos++){
      float4 k4 = *(const float4*)&Ks[pos*KP + sub*4];
      float dd = qn[0]*k4.x + qn[1]*k4.y + qn[2]*k4.z + qn[3]*k4.w;
      dd += __shfl_xor(dd, 1); dd += __shfl_xor(dd, 2);
      float pp = __expf(dd);
      l += pp;
      float4 v4 = *(const float4*)&Vs[pos*KP + sub*4];
      acc[0] += pp*v4.x;
      acc[1] += pp*v4.y;
      acc[2] += pp*v4.z;
      acc[3] += pp*v4.w;
    }
    __syncthreads();
  }
  if (qv){
    float li = 1.f / fmaxf(l, 1e-30f);
    #pragma unroll
    for (int j = 0; j < 4; j++)
      Out[(size_t)bb*obs + (size_t)(h*16 + sub*4 + j)*NQ + qi] = acc[j]*li;
  }
}

// ---------------- xw attention with INLINE kvlat conv + K-norm (proven R28) ----------------
__global__ __launch_bounds__(256) void attn4lat_k(
    const float* __restrict__ Q, long qbs,
    const float* __restrict__ latr, const void* __restrict__ kvw,
    float* __restrict__ Out, long obs, int NQ, float scale,
    const float* __restrict__ flagp)
{
  __shared__ __align__(16) float Ks[16*KP];
  __shared__ __align__(16) float Vs[16*KP];
  bool bf = *flagp > 0.5f;
  int tid = threadIdx.x;
  int h = blockIdx.y, bb = blockIdx.z;
  {
    int pos = tid & 15, d = tid >> 4;
    const float* lr = latr + (size_t)bb*2048;
    float kk = 0.f, vv = 0.f;
    for (int c = 0; c < 128; c++){
      float xv = lr[(size_t)c*16 + pos];
      kk += rdv(kvw, (size_t)(h*16 + d)*128 + c, bf) * xv;
      vv += rdv(kvw, (size_t)(128 + h*16 + d)*128 + c, bf) * xv;
    }
    Ks[pos*KP + d] = kk;
    Vs[pos*KP + d] = vv;
  }
  __syncthreads();
  if (tid < 16){
    float ss = 0.f;
    #pragma unroll
    for (int d = 0; d < 16; d++){ float v = Ks[tid*KP + d]; ss += v*v; }
    float iv = 1.f / fmaxf(sqrtf(ss), 1e-12f);
    #pragma unroll
    for (int d = 0; d < 16; d++) Ks[tid*KP + d] *= iv;
  }
  __syncthreads();
  int sub = tid & 3;
  int qi = blockIdx.x*64 + (tid >> 2);
  float qn[4]; float acc[4] = {0,0,0,0}; float l = 0.f;
  {
    float s = 0.f;
    #pragma unroll
    for (int j = 0; j < 4; j++){
      qn[j] = Q[(size_t)bb*qbs + (size_t)(h*16 + sub*4 + j)*NQ + qi];
      s += qn[j]*qn[j];
    }
    s += __shfl_xor(s, 1); s += __shfl_xor(s, 2);
    float inv = scale / fmaxf(sqrtf(s), 1e-12f);
    #pragma unroll
    for (int j = 0; j < 4; j++) qn[j] *= inv;
  }
  for (int pos = 0; pos < 16; pos++){
    float4 k4 = *(const float4*)&Ks[pos*KP + sub*4];
    float dd = qn[0]*k4.x + qn[1]*k4.y + qn[2]*k4.z + qn[3]*k4.w;
    dd += __shfl_xor(dd, 1); dd += __shfl_xor(dd, 2);
    float pp = __expf(dd);
    l += pp;
    float4 v4 = *(const float4*)&Vs[pos*KP + sub*4];
    acc[0] += pp*v4.x;
    acc[1] += pp*v4.y;
    acc[2] += pp*v4.z;
    acc[3] += pp*v4.w;
  }
  float li = 1.f / fmaxf(l, 1e-30f);
  #pragma unroll
  for (int j = 0; j < 4; j++)
    Out[(size_t)bb*obs + (size_t)(h*16 + sub*4 + j)*NQ + qi] = acc[j]*li;
}

// ---------------- latent-read attention, split-K partials (S=144, proven R29) ----------------
__global__ void latpart_k(const float* __restrict__ ql, const float* __restrict__ kvx,
                          long kbs, float* __restrict__ part, int NK, int S){
  int s = blockIdx.x, h = blockIdx.y, bb = blockIdx.z;
  int t = threadIdx.x;
  int q = t & 15, sub = (t >> 4) & 3;
  float qn[16]; float ss = 0.f;
  #pragma unroll
  for (int d = 0; d < 16; d++){
    qn[d] = ql[(size_t)bb*2048 + (size_t)(h*16+d)*16 + q];
    ss += qn[d]*qn[d];
  }
  float inv = 0.25f / fmaxf(sqrtf(ss), 1e-12f);
  #pragma unroll
  for (int d = 0; d < 16; d++) qn[d] *= inv;
  float l = 0.f, acc[16];
  #pragma unroll
  for (int d = 0; d < 16; d++) acc[d] = 0.f;
  int chunk = NK / S, c4 = chunk >> 2;
  int k0 = s*chunk + sub*c4, k1 = k0 + c4;
  const float* kb = kvx + (size_t)bb*kbs;
  for (int pos = k0; pos < k1; pos++){
    float dot = 0.f;
    #pragma unroll
    for (int d = 0; d < 16; d++) dot += qn[d]*kb[(size_t)(h*16+d)*NK + pos];
    float pp = __expf(dot);
    l += pp;
    #pragma unroll
    for (int d = 0; d < 16; d++)
      acc[d] += pp*kb[(size_t)(128 + h*16+d)*NK + pos];
  }
  l += __shfl_xor(l, 16); l += __shfl_xor(l, 32);
  #pragma unroll
  for (int d = 0; d < 16; d++){
    acc[d] += __shfl_xor(acc[d], 16);
    acc[d] += __shfl_xor(acc[d], 32);
  }
  if ((t >> 4) == 0){
    size_t idx = (size_t)((((bb*8 + h)*16 + q)*S) + s)*18;
    part[idx] = l;
    #pragma unroll
    for (int d = 0; d < 16; d++) part[idx+1+d] = acc[d];
  }
}

__global__ void latcomb_k(const float* __restrict__ part, float* __restrict__ latr, int S){
  int i = blockIdx.x*blockDim.x + threadIdx.x;   // 4096 total
  int d = i & 15, q = (i >> 4) & 15, h = (i >> 8) & 7, bb = i >> 11;
  size_t base = (size_t)(((bb*8 + h)*16 + q)*S)*18;
  float L = 0.f, a = 0.f;
  for (int s = 0; s < S; s++){
    const float* ps = part + base + (size_t)s*18;
    L += ps[0];
    a += ps[1+d];
  }
  latr[(size_t)bb*2048 + (size_t)(h*16+d)*16 + q] = a / fmaxf(L, 1e-30f);
}

extern "C" void kernel_launch(void* const* d_in, const int* in_sizes, int n_in,
                              void* d_out, int out_size, void* d_ws, size_t ws_size,
                              hipStream_t stream){
  const int B = 2, C = 128, HW = 2304;
  const void* x_in        = d_in[0];
  const void* g1          = d_in[1];
  const void* b1          = d_in[2];
  const void* loc_qkv_w   = d_in[3];
  const void* loc_proj_w  = d_in[4];
  const void* loc_proj_b  = d_in[5];
  const void* glob_qkv_w  = d_in[6];
  const void* glob_proj_w = d_in[7];
  const void* glob_proj_b = d_in[8];
  const void* fuse_w1     = d_in[9];
  const void* fuse_b1     = d_in[10];
  const void* fuse_w2     = d_in[11];
  const void* fuse_b2     = d_in[12];
  const void* glat        = d_in[13];
  const void* blat        = d_in[14];
  const void* latents     = d_in[15];
  const void* qlat_w      = d_in[16];
  const void* kvx_w       = d_in[17];
  const void* qx_w        = d_in[18];
  const void* kvlat_w     = d_in[19];
  const void* lat_proj_w  = d_in[20];
  const void* lat_proj_b  = d_in[21];
  const void* g2          = d_in[22];
  const void* b2          = d_in[23];
  const void* ffn_w1      = d_in[24];
  const void* ffn_b1      = d_in[25];
  const void* ffn_w2      = d_in[26];
  const void* ffn_b2      = d_in[27];

  // ---- workspace layout VERBATIM (R8..R18) ----
  float* ws = (float*)d_ws;
  float* P  = ws + 0;
  float* N  = ws + 589824;
  float* A  = ws + 1179648;
  float* Q  = ws + 1769472;
  float* FLAG = ws + 4128768;

  float* qkv   = Q;                 // 1,769,472
  float* L     = Q + 1769472;       // 589,824
  float* qkvc  = Q + 36864;
  float* gatt  = Q + 147456;
  float* gproj = Q + 184320;
  float* kvx   = Q;                 // 1,179,648
  float* qlat  = Q + 1181696;
  float* latr  = Q + 1185792;
  float* part  = Q + 1198080;       // 663,552 (S=144)
  float* ffh   = Q;                 // 2,359,296

  dim3 blk(256);
  dim3 blk512(512);

  detect_k<<<1, 64, 0, stream>>>(x_in, FLAG);
  cvt_k<<<2304, blk, 0, stream>>>(x_in, P, 589824, FLAG);

  // ---- BioAttentionFusion branch ----
  ln2dw_k<<<dim3(144,B), blk, 0, stream>>>(P, g1, b1, N, C, HW, FLAG);
  convmfma_k<<<dim3(144,3,B), blk, 0, stream>>>(N,(long)C*HW,C, nullptr,0,0, loc_qkv_w,nullptr,nullptr, qkv,0,384,HW,0, 128,256, 0,nullptr,nullptr, 0,0, nullptr,nullptr,0,0, 1, FLAG);
  flat_mfma_k<<<dim3(36,8,B), blk512, 0, stream>>>(qkv,(long)384*HW,0, qkv,(long)384*HW,128,256, A,(long)C*HW, HW,HW,0.25f);
  convmfma_k<<<dim3(144,2,B), blk, 0, stream>>>(A,(long)C*HW,C, nullptr,0,0, loc_proj_w,loc_proj_b,nullptr, L,0,C,HW,0, 0,0, 0,nullptr,nullptr, 0,0, nullptr,nullptr,0,0, 0, FLAG);
  // pooled global qkv: pool4 + conv + normk fused
  convmfma_k<<<dim3(9,6,B), blk, 0, stream>>>(N,(long)C*HW,C, nullptr,0,0, glob_qkv_w,nullptr,nullptr, qkvc,0,384,144,0, 128,256, 0,nullptr,nullptr, 1,0, nullptr,nullptr,0,0, 0, FLAG);
  attn4_k<<<dim3(3,8,B), blk, 0, stream>>>(qkvc,(long)384*144,0, qkvc,(long)384*144,128,256, gatt,(long)C*144, 144,144,0.25f);
  convmfma_k<<<dim3(9,2,B), blk, 0, stream>>>(gatt,(long)C*144,C, nullptr,0,0, glob_proj_w,glob_proj_b,nullptr, gproj,0,C,144,0, 0,0, 0,nullptr,nullptr, 0,0, nullptr,nullptr,0,0, 0, FLAG);
  // fuse1: in2 = gproj with inline bilinear upsample
  convmfma_k<<<dim3(144,2,B), blk, 0, stream>>>(L,(long)C*HW,C, gproj,(long)C*144,C, fuse_w1,fuse_b1,nullptr, N,0,C,HW,1, 0,0, 0,nullptr,nullptr, 0,1, nullptr,nullptr,0,0, 0, FLAG);
  convmfma_k<<<dim3(144,2,B), blk, 0, stream>>>(N,(long)C*HW,C, nullptr,0,0, fuse_w2,fuse_b2,P, P,0,C,HW,0, 0,0, 0,nullptr,nullptr, 0,0, nullptr,nullptr,0,0, 0, FLAG);

  // ---- LatentMixer branch (LN fused; kvx+qx merged via osplit; ot2 dual-tile) ----
  convmfma_k<<<dim3(144,3,B), blk, 0, stream>>>(P,(long)C*HW,C, nullptr,0,0, kvx_w,nullptr,nullptr, kvx,0,256,HW,0, 0,128, 1,glat,blat, 0,0, qx_w,A,128,256, 1, FLAG);
  qlat_k<<<16, blk, 0, stream>>>(latents, qlat_w, qlat, FLAG);
  latpart_k<<<dim3(144,8,B), 64, 0, stream>>>(qlat, kvx, (long)256*HW, part, HW, 144);
  latcomb_k<<<16, blk, 0, stream>>>(part, latr, 144);
  attn4lat_k<<<dim3(36,8,B), blk, 0, stream>>>(A,(long)C*HW, latr, kvlat_w, N,(long)C*HW, HW, 0.25f, FLAG);   // N = xw
  convmfma_k<<<dim3(144,2,B), blk, 0, stream>>>(N,(long)C*HW,C, nullptr,0,0, lat_proj_w,lat_proj_b,P, P,0,C,HW,0, 0,0, 0,nullptr,nullptr, 0,0, nullptr,nullptr,0,0, 0, FLAG); // P = x2

  // ---- FFN branch (LN fused into ffn1; ot2 dual-tile) ----
  convmfma_k<<<dim3(144,4,B), blk, 0, stream>>>(P,(long)C*HW,C, nullptr,0,0, ffn_w1,ffn_b1,nullptr, ffh,0,512,HW,1, 0,0, 1,g2,b2, 0,0, nullptr,nullptr,0,0, 1, FLAG);
  convmfma_k<<<dim3(144,2,B), blk, 0, stream>>>(ffh,(long)512*HW,512, nullptr,0,0, ffn_w2,ffn_b2,P, d_out,1,C,HW,0, 0,0, 0,nullptr,nullptr, 0,0, nullptr,nullptr,0,0, 0, FLAG);
}